// Round 3
// baseline (2375.924 us; speedup 1.0000x reference)
//
#include <hip/hip_runtime.h>
#include <math.h>

#define BB 4
#define C1 128
#define H1 128
#define W1 128
#define C2 256
#define H2 64
#define W2 64
#define LSEQ 4096
#define HID 256
#define DIN 512
#define DST 16
#define DTR 16
#define NL 4
#define NCHUNK 64
#define LCH 64

typedef unsigned short u16;
using short8 = __attribute__((ext_vector_type(8))) short;
using f32x4  = __attribute__((ext_vector_type(4))) float;
using f32x2  = __attribute__((ext_vector_type(2))) float;

static __device__ __forceinline__ float dsilu(float x){
    return x / (1.0f + __expf(-x));
}
static __device__ __forceinline__ u16 f2bf(float f){
    unsigned u = __float_as_uint(f);
    u += 0x7FFF + ((u >> 16) & 1);
    return (u16)(u >> 16);
}
static __device__ __forceinline__ float bf2f(u16 v){
    return __uint_as_float(((unsigned)v) << 16);
}

#define GLL16(g, l) __builtin_amdgcn_global_load_lds( \
    (const __attribute__((address_space(1))) void*)(g), \
    (__attribute__((address_space(3))) void*)(l), 16, 0, 0)
#define GLL4(g, l) __builtin_amdgcn_global_load_lds( \
    (const __attribute__((address_space(1))) void*)(g), \
    (__attribute__((address_space(3))) void*)(l), 4, 0, 0)

#define VMW(n) asm volatile("s_waitcnt vmcnt(" #n ")" ::: "memory")

static __device__ __forceinline__ void blockbar(){
    asm volatile("" ::: "memory");
    __builtin_amdgcn_s_barrier();
    asm volatile("" ::: "memory");
}

// grid-wide spin barrier; requires all blocks co-resident (guaranteed by
// launch config: 512 blocks, 40KB LDS, launch_bounds(256,2) -> 2 blocks/CU)
static __device__ __forceinline__ void gridbar(unsigned* bar, unsigned target){
    __threadfence();
    __syncthreads();
    if(threadIdx.x == 0){
        atomicAdd(bar, 1u);
        while(atomicAdd(bar, 0u) < target){ __builtin_amdgcn_s_sleep(2); }
    }
    __syncthreads();
    __threadfence();
}

// ---------------- weight prep ----------------
__global__ void f2bf_kernel(const float* __restrict__ src, u16* __restrict__ dst){
    int idx = blockIdx.x * 256 + threadIdx.x;
    dst[idx] = f2bf(src[idx]);
}
// combined dt/BC weight: wcomb[layer][n][k], n<512: (dpw @ xpw[0:16])[n][k];
// n in 512..543: xpw rows 16..47; rest zero.
__global__ void wdt_prep_kernel(const float* __restrict__ xpw, const float* __restrict__ dpw,
                                u16* __restrict__ wcomb){
    int idx = blockIdx.x * 256 + threadIdx.x;   // 4*640*512 = 1,310,720
    int k = idx & 511;
    int n = (idx >> 9) % 640;
    int layer = idx / (640*512);
    u16 val = 0;
    if(n < 512){
        const float* dp = dpw + ((long)layer*512 + n)*16;
        const float* xp = xpw + (long)layer*48*512 + k;
        float acc = 0.f;
        #pragma unroll
        for(int r = 0; r < 16; ++r) acc = fmaf(dp[r], xp[(long)r*512], acc);
        val = f2bf(acc);
    } else if(n < 544){
        int row = n - 512 + 16;
        val = f2bf(xpw[((long)layer*48 + row)*512 + k]);
    }
    wcomb[((long)layer*640 + n)*512 + k] = val;
}
// conv2_w [co][ci][kh][kw] -> w2 [co][p=kh*3+kw][ci] bf16
__global__ void c2w_prep_kernel(const float* __restrict__ src, u16* __restrict__ dst){
    int idx = blockIdx.x * 256 + threadIdx.x;   // 294912
    int ci = idx & 127, p = (idx >> 7) % 9, co = idx / (9*128);
    int kh = p / 3, kw = p - 3*kh;
    dst[idx] = f2bf(src[((co*128 + ci)*3 + kh)*3 + kw]);
}
// zero only the 1-wide border of xt [b][130][130][128]
__global__ void xt_border_kernel(unsigned* __restrict__ xt){
    int idx = blockIdx.x * 256 + threadIdx.x;   // 516 blocks -> 132,096 threads
    int c2 = idx & 63;
    int cell = (idx >> 6) % 516;
    int b = idx / (516*64);
    int ih, iw;
    if(cell < 130){ ih = 0; iw = cell; }
    else if(cell < 260){ ih = 129; iw = cell - 130; }
    else if(cell < 388){ iw = 0; ih = cell - 259; }
    else { iw = 129; ih = cell - 387; }
    xt[((long)(b*130 + ih)*130 + iw)*64 + c2] = 0;
}
__global__ void bar_init_kernel(unsigned* __restrict__ bar){
    bar[threadIdx.x] = 0;   // 16 threads
}

// ---------------- conv1 via LDS row staging ----------------
__global__ __launch_bounds__(256) void conv1_kernel(
        const float* __restrict__ x, const float* __restrict__ w,
        const float* __restrict__ bias, float* __restrict__ y){
    __shared__ float xs[9][260];
    int oh = blockIdx.x, b = blockIdx.y;
    int tid = threadIdx.x;
    #pragma unroll
    for(int r = 0; r < 9; ++r){
        int ci = r / 3, kh = r - 3*ci;
        int ih = 2*oh - 1 + kh;
        float v = 0.f;
        if(ih >= 0) v = x[((b*3 + ci)*256 + ih)*256 + tid];
        xs[r][tid + 1] = v;
        if(tid == 0) xs[r][0] = 0.f;
    }
    __syncthreads();
    int co = tid >> 1, h = tid & 1;
    float wr[27];
    #pragma unroll
    for(int j = 0; j < 27; ++j) wr[j] = w[co*27 + j];
    float bz = bias[co];
    long obase = ((long)((b*128 + co)*128 + oh))*128 + h*64;
    #pragma unroll 4
    for(int i = 0; i < 64; ++i){
        int iw0 = 2*(h*64 + i);
        float acc = bz;
        #pragma unroll
        for(int r = 0; r < 9; ++r){
            acc = fmaf(xs[r][iw0+0], wr[r*3+0], acc);
            acc = fmaf(xs[r][iw0+1], wr[r*3+1], acc);
            acc = fmaf(xs[r][iw0+2], wr[r*3+2], acc);
        }
        y[obase + i] = acc;
    }
}

// ---------------- GN stats ----------------
__global__ void zero_stats_kernel(float* __restrict__ stats){
    stats[threadIdx.x] = 0.0f;   // 64 threads
}

__global__ void gn_stats_kernel(const float* __restrict__ x, float* __restrict__ stats,
                                int elems_per_group){
    const int EPB = 16384;
    long base = (long)blockIdx.x * EPB;
    int g = (int)(base / elems_per_group);
    float s = 0.f, ss = 0.f;
    for(int j = threadIdx.x; j < EPB; j += 256){
        float v = x[base + j];
        s += v; ss += v*v;
    }
    #pragma unroll
    for(int off = 32; off; off >>= 1){
        s  += __shfl_down(s,  off);
        ss += __shfl_down(ss, off);
    }
    __shared__ float ls[4], lss[4];
    int wid = threadIdx.x >> 6, lane = threadIdx.x & 63;
    if(lane == 0){ ls[wid] = s; lss[wid] = ss; }
    __syncthreads();
    if(threadIdx.x == 0){
        atomicAdd(&stats[g],      ls[0]+ls[1]+ls[2]+ls[3]);
        atomicAdd(&stats[32+g], lss[0]+lss[1]+lss[2]+lss[3]);
    }
}

// ---------------- GN1 apply + SiLU + NCHW -> padded channels-last bf16 ----------------
__global__ void gn1_transform_kernel(const float* __restrict__ y1, const float* __restrict__ stats,
                                     const float* __restrict__ w, const float* __restrict__ bias,
                                     u16* __restrict__ xt){
    __shared__ float tile[32][33];
    int b = blockIdx.z >> 7, ih = blockIdx.z & 127;
    int c0 = blockIdx.y * 32, w0 = blockIdx.x * 32;
    int tx = threadIdx.x, ty = threadIdx.y;   // 32 x 8
    const float cnt = 16.f * 128.f * 128.f;
    #pragma unroll
    for(int i = 0; i < 4; ++i){
        int ci = c0 + ty + i*8;
        int g = b*8 + (ci >> 4);
        float mean = stats[g] / cnt;
        float var  = stats[32+g] / cnt - mean*mean;
        float rstd = rsqrtf(var + 1e-5f);
        float v = y1[(((long)(b*C1 + ci))*H1 + ih)*W1 + w0 + tx];
        tile[ty + i*8][tx] = dsilu((v - mean) * rstd * w[ci] + bias[ci]);
    }
    __syncthreads();
    #pragma unroll
    for(int i = 0; i < 4; ++i){
        int iwl = ty + i*8;
        xt[((long)(b*130 + ih + 1)*130 + (w0 + iwl + 1))*128 + c0 + tx] = f2bf(tile[tx][iwl]);
    }
}

// ---------------- conv2 as bf16 MFMA implicit GEMM (tile 64x128, 3-stage) ----------------
__global__ __launch_bounds__(256) void conv2gemm_bf16_kernel(
        const u16* __restrict__ xt, const u16* __restrict__ w2,
        const float* __restrict__ bias, float* __restrict__ y2t){
    __shared__ u16 Asm[3][64*32];    // 12 KB
    __shared__ u16 Bsm[3][128*32];   // 24 KB
    int m0 = blockIdx.x * 64, n0 = blockIdx.y * 128;
    int tid = threadIdx.x;
    // A staging: 1 load/thread (64 rows x 32 k)
    long abase;
    {
        int r = tid >> 2;
        int kq = ((tid & 3) ^ ((r >> 1) & 3)) * 8;
        int m = m0 + r;
        int b = m >> 12, oh = (m >> 6) & 63, ow = m & 63;
        abase = ((long)(b*130 + 2*oh)*130 + 2*ow)*128 + kq;
    }
    int lda = tid*8;
    // B staging: 2 loads/thread (128 rows x 32 k)
    const u16* bbase[2]; int ldb[2];
    #pragma unroll
    for(int it = 0; it < 2; ++it){
        int c = it*256 + tid;
        int r = c >> 2;
        int kq = ((c & 3) ^ ((r >> 1) & 3)) * 8;
        bbase[it] = w2 + (long)(n0 + r)*1152 + kq;
        ldb[it] = c*8;
    }
    int wave = tid >> 6, lane = tid & 63;
    int wr = wave >> 1, wc = wave & 1;
    int lm = lane & 15, lq = lane >> 4;
    int swq = (lq ^ ((lm >> 1) & 3)) * 8;
    f32x4 acc[2][4] = {};
    // prologue: tiles 0,1
    #pragma unroll
    for(int pt = 0; pt < 2; ++pt){
        int p = pt >> 2, cs = pt & 3;
        int kh = p / 3, kw = p - 3*kh;
        int ao = (kh*130 + kw)*128 + cs*32;
        GLL16(xt + abase + ao, &Asm[pt][lda]);
        #pragma unroll
        for(int it = 0; it < 2; ++it)
            GLL16(bbase[it] + pt*32, &Bsm[pt][ldb[it]]);
    }
    for(int kk = 0; kk < 36; ++kk){
        int cur = kk % 3;
        if(kk + 2 < 36){
            int k2 = kk + 2;
            int nxt = (kk + 2) % 3;
            int p = k2 >> 2, cs = k2 & 3;
            int kh = p / 3, kw = p - 3*kh;
            int ao = (kh*130 + kw)*128 + cs*32;
            GLL16(xt + abase + ao, &Asm[nxt][lda]);
            #pragma unroll
            for(int it = 0; it < 2; ++it)
                GLL16(bbase[it] + k2*32, &Bsm[nxt][ldb[it]]);
            VMW(6);
        } else if(kk + 1 < 36){
            VMW(3);
        } else {
            VMW(0);
        }
        blockbar();
        short8 af[2], bf[4];
        #pragma unroll
        for(int i = 0; i < 2; ++i)
            af[i] = *(const short8*)&Asm[cur][(wr*32 + i*16 + lm)*32 + swq];
        #pragma unroll
        for(int j = 0; j < 4; ++j)
            bf[j] = *(const short8*)&Bsm[cur][(wc*64 + j*16 + lm)*32 + swq];
        #pragma unroll
        for(int i = 0; i < 2; ++i)
            #pragma unroll
            for(int j = 0; j < 4; ++j)
                acc[i][j] = __builtin_amdgcn_mfma_f32_16x16x32_bf16(af[i], bf[j], acc[i][j], 0, 0, 0);
        __builtin_amdgcn_sched_barrier(0);
        blockbar();
    }
    #pragma unroll
    for(int i = 0; i < 2; ++i){
        long row = m0 + wr*32 + i*16 + lq*4;
        #pragma unroll
        for(int j = 0; j < 4; ++j){
            int col = n0 + wc*64 + j*16 + lm;
            float bz = bias[col];
            #pragma unroll
            for(int r = 0; r < 4; ++r)
                y2t[(row + r)*256L + col] = acc[i][j][r] + bz;
        }
    }
}

// ---------------- GN2 stats over [m][c] ----------------
__global__ void gn2t_stats_kernel(const float* __restrict__ y2t, float* __restrict__ stats){
    int b = blockIdx.y;
    long row0 = (long)b*LSEQ + blockIdx.x*64;
    int c = threadIdx.x;
    float s = 0.f, ss = 0.f;
    for(int r = 0; r < 64; ++r){
        float v = y2t[(row0 + r)*C2 + c];
        s += v; ss += v*v;
    }
    #pragma unroll
    for(int off = 16; off; off >>= 1){
        s  += __shfl_down(s,  off);
        ss += __shfl_down(ss, off);
    }
    if((c & 31) == 0){
        int g = b*8 + (c >> 5);
        atomicAdd(&stats[g], s);
        atomicAdd(&stats[32+g], ss);
    }
}

// ---------------- GN2 apply + SiLU -> s, fused LayerNorm(layer 0) -> xln_bf ----------------
__global__ void gn2t_apply_ln_kernel(const float* __restrict__ y2t, const float* __restrict__ stats,
                                     const float* __restrict__ gw, const float* __restrict__ gb,
                                     const float* __restrict__ lw, const float* __restrict__ lb,
                                     float* __restrict__ s, u16* __restrict__ xln){
    long row = blockIdx.x;                        // 16384 rows
    int c = threadIdx.x;                          // 256
    int b = (int)(row >> 12);
    int g = b*8 + (c >> 5);
    const float cnt = 32.f * (float)LSEQ;
    float mean = stats[g] / cnt;
    float var  = stats[32+g] / cnt - mean*mean;
    float rstd = rsqrtf(var + 1e-5f);
    float v = dsilu((y2t[row*HID + c] - mean) * rstd * gw[c] + gb[c]);
    s[row*HID + c] = v;
    float sm = v, sq = v*v;
    #pragma unroll
    for(int off = 32; off; off >>= 1){
        sm += __shfl_down(sm, off);
        sq += __shfl_down(sq, off);
    }
    __shared__ float pa[4], pb[4], res[2];
    int wid = c >> 6, lane = c & 63;
    if(lane == 0){ pa[wid] = sm; pb[wid] = sq; }
    __syncthreads();
    if(c == 0){
        float t  = pa[0]+pa[1]+pa[2]+pa[3];
        float tt = pb[0]+pb[1]+pb[2]+pb[3];
        float m2 = t / 256.f;
        float v2 = tt / 256.f - m2*m2;
        res[0] = m2; res[1] = rsqrtf(v2 + 1e-5f);
    }
    __syncthreads();
    xln[row*HID + c] = f2bf((v - res[0]) * res[1] * lw[c] + lb[c]);
}

// ---------------- bf16 MFMA GEMM: C[M,N] = A[M,K] * B[N,K]^T (3-stage) ----------------
// mode 2: bf16 store (used for in_proj)
__global__ __launch_bounds__(256) void gemm_bf16_kernel(
        const u16* __restrict__ A, const u16* __restrict__ B, void* __restrict__ Cv,
        int K, int Nact, int ldc, int mode){
    __shared__ u16 Asm[3][128*32];
    __shared__ u16 Bsm[3][128*32];
    int m0 = blockIdx.x * 128, n0 = blockIdx.y * 128;
    int tid = threadIdx.x;
    int wave = tid >> 6, lane = tid & 63;
    int wr = wave >> 1, wc = wave & 1;
    int lm = lane & 15, lq = lane >> 4;
    int swq = (lq ^ ((lm >> 1) & 3)) * 8;
    const u16* ag[2]; const u16* bg[2]; int ldst[2];
    #pragma unroll
    for(int it = 0; it < 2; ++it){
        int c = it*256 + tid;
        int r = c >> 2;
        int kq = ((c & 3) ^ ((r >> 1) & 3)) * 8;
        ag[it] = A + (long)(m0 + r)*K + kq;
        bg[it] = B + (long)(n0 + r)*K + kq;
        ldst[it] = c*8;
    }
    f32x4 acc[4][4] = {};
    int nk = K >> 5;
    #pragma unroll
    for(int pt = 0; pt < 2; ++pt){
        int ko = pt << 5;
        #pragma unroll
        for(int it = 0; it < 2; ++it){
            GLL16(ag[it] + ko, &Asm[pt][ldst[it]]);
            GLL16(bg[it] + ko, &Bsm[pt][ldst[it]]);
        }
    }
    for(int kt = 0; kt < nk; ++kt){
        int cur = kt % 3;
        if(kt + 2 < nk){
            int nxt = (kt + 2) % 3;
            int ko = (kt + 2) << 5;
            #pragma unroll
            for(int it = 0; it < 2; ++it){
                GLL16(ag[it] + ko, &Asm[nxt][ldst[it]]);
                GLL16(bg[it] + ko, &Bsm[nxt][ldst[it]]);
            }
            VMW(8);
        } else if(kt + 1 < nk){
            VMW(4);
        } else {
            VMW(0);
        }
        blockbar();
        short8 af[4], bf[4];
        #pragma unroll
        for(int i = 0; i < 4; ++i){
            af[i] = *(const short8*)&Asm[cur][(wr*64 + i*16 + lm)*32 + swq];
            bf[i] = *(const short8*)&Bsm[cur][(wc*64 + i*16 + lm)*32 + swq];
        }
        #pragma unroll
        for(int i = 0; i < 4; ++i)
            #pragma unroll
            for(int j = 0; j < 4; ++j)
                acc[i][j] = __builtin_amdgcn_mfma_f32_16x16x32_bf16(af[i], bf[j], acc[i][j], 0, 0, 0);
        __builtin_amdgcn_sched_barrier(0);
        blockbar();
    }
    #pragma unroll
    for(int i = 0; i < 4; ++i){
        long row = m0 + wr*64 + i*16 + lq*4;
        #pragma unroll
        for(int j = 0; j < 4; ++j){
            int col = n0 + wc*64 + j*16 + lm;
            if(col < Nact){
                #pragma unroll
                for(int r = 0; r < 4; ++r){
                    long idx = (row + r)*(long)ldc + col;
                    if(mode == 2) ((u16*)Cv)[idx] = f2bf(acc[i][j][r]);
                    else          ((float*)Cv)[idx] = acc[i][j][r];
                }
            }
        }
    }
}

// ---------------- fused dt-proj (softplus) + x_proj B/C GEMM (3-stage) ----------------
__global__ __launch_bounds__(256) void gemm_dtbc_kernel(
        const u16* __restrict__ A, const u16* __restrict__ B,
        const float* __restrict__ dpb, u16* __restrict__ dv,
        float* __restrict__ xdbl32){
    __shared__ u16 Asm[3][128*32];
    __shared__ u16 Bsm[3][128*32];
    int m0 = blockIdx.x * 128, n0 = blockIdx.y * 128;
    int tid = threadIdx.x;
    int wave = tid >> 6, lane = tid & 63;
    int wr = wave >> 1, wc = wave & 1;
    int lm = lane & 15, lq = lane >> 4;
    int swq = (lq ^ ((lm >> 1) & 3)) * 8;
    // last n-tile (n0=512) has only 32 valid cols -> skip dead MFMAs
    int jlim = (n0 < 512) ? 4 : ((wc == 0) ? 2 : 0);
    const u16* ag[2]; const u16* bg[2]; int ldst[2];
    #pragma unroll
    for(int it = 0; it < 2; ++it){
        int c = it*256 + tid;
        int r = c >> 2;
        int kq = ((c & 3) ^ ((r >> 1) & 3)) * 8;
        ag[it] = A + (long)(m0 + r)*512 + kq;
        bg[it] = B + (long)(n0 + r)*512 + kq;
        ldst[it] = c*8;
    }
    f32x4 acc[4][4] = {};
    #pragma unroll
    for(int pt = 0; pt < 2; ++pt){
        int ko = pt << 5;
        #pragma unroll
        for(int it = 0; it < 2; ++it){
            GLL16(ag[it] + ko, &Asm[pt][ldst[it]]);
            GLL16(bg[it] + ko, &Bsm[pt][ldst[it]]);
        }
    }
    for(int kt = 0; kt < 16; ++kt){
        int cur = kt % 3;
        if(kt + 2 < 16){
            int nxt = (kt + 2) % 3;
            int ko = (kt + 2) << 5;
            #pragma unroll
            for(int it = 0; it < 2; ++it){
                GLL16(ag[it] + ko, &Asm[nxt][ldst[it]]);
                GLL16(bg[it] + ko, &Bsm[nxt][ldst[it]]);
            }
            VMW(8);
        } else if(kt + 1 < 16){
            VMW(4);
        } else {
            VMW(0);
        }
        blockbar();
        short8 af[4];
        #pragma unroll
        for(int i = 0; i < 4; ++i)
            af[i] = *(const short8*)&Asm[cur][(wr*64 + i*16 + lm)*32 + swq];
        for(int j = 0; j < jlim; ++j){
            short8 bf = *(const short8*)&Bsm[cur][(wc*64 + j*16 + lm)*32 + swq];
            #pragma unroll
            for(int i = 0; i < 4; ++i)
                acc[i][j] = __builtin_amdgcn_mfma_f32_16x16x32_bf16(af[i], bf, acc[i][j], 0, 0, 0);
        }
        __builtin_amdgcn_sched_barrier(0);
        blockbar();
    }
    if(n0 < 512){
        #pragma unroll
        for(int i = 0; i < 4; ++i){
            long row = m0 + wr*64 + i*16 + lq*4;
            #pragma unroll
            for(int j = 0; j < 4; ++j){
                int col = n0 + wc*64 + j*16 + lm;
                float bz = dpb[col];
                #pragma unroll
                for(int r = 0; r < 4; ++r){
                    float v = acc[i][j][r] + bz;
                    v = (v > 20.f) ? v : __logf(1.f + __expf(v));
                    dv[(row + r)*512L + col] = f2bf(v);
                }
            }
        }
    } else {
        #pragma unroll
        for(int i = 0; i < 4; ++i){
            long row = m0 + wr*64 + i*16 + lq*4;
            #pragma unroll
            for(int j = 0; j < 4; ++j){
                int lcol = wc*64 + j*16 + lm;     // 0..127, valid < 32
                if(lcol < 32){
                    #pragma unroll
                    for(int r = 0; r < 4; ++r)
                        xdbl32[(row + r)*32L + lcol] = acc[i][j][r];
                }
            }
        }
    }
}

// ---------------- out_proj + residual + LayerNorm fused (tile M=32, 3-stage) ----------------
__global__ __launch_bounds__(256) void gemm_out_ln_kernel(
        const u16* __restrict__ A, const u16* __restrict__ B,
        float* __restrict__ s, u16* __restrict__ xln,
        const float* __restrict__ lw, const float* __restrict__ lb){
    __shared__ u16 Asm[3][32*32];    // 6 KB
    __shared__ u16 Bsm[3][256*32];   // 48 KB
    __shared__ float lnred[2][2][16][2];
    int m0 = blockIdx.x * 32;
    int tid = threadIdx.x;
    int wave = tid >> 6, lane = tid & 63;
    int wr = wave >> 1, wc = wave & 1;
    int lm = lane & 15, lq = lane >> 4;
    int swq = (lq ^ ((lm >> 1) & 3)) * 8;
    // A: 2 x 4B loads/thread (32 rows x 32 k)
    const u16* agA[2]; int lda[2];
    #pragma unroll
    for(int it = 0; it < 2; ++it){
        int c = it*256 + tid;
        int r = c >> 4;
        int kp = (c & 15) * 2;
        int kel = ((((c & 15) >> 2) ^ ((r >> 1) & 3)) << 3) + (kp & 7);
        agA[it] = A + (long)(m0 + r)*512 + kel;
        lda[it] = c*2;     // u16 index (byte = c*4)
    }
    // B: 4 x 16B loads/thread (256 rows x 32 k)
    const u16* bg[4]; int ldb[4];
    #pragma unroll
    for(int it = 0; it < 4; ++it){
        int c = it*256 + tid;
        int r = c >> 2;
        int kq = ((c & 3) ^ ((r >> 1) & 3)) * 8;
        bg[it] = B + (long)r*512 + kq;
        ldb[it] = c*8;
    }
    f32x4 acc[8] = {};
    #pragma unroll
    for(int pt = 0; pt < 2; ++pt){
        int ko = pt << 5;
        #pragma unroll
        for(int it = 0; it < 2; ++it) GLL4(agA[it] + ko, &Asm[pt][lda[it]]);
        #pragma unroll
        for(int it = 0; it < 4; ++it) GLL16(bg[it] + ko, &Bsm[pt][ldb[it]]);
    }
    for(int kt = 0; kt < 16; ++kt){
        int cur = kt % 3;
        if(kt + 2 < 16){
            int nxt = (kt + 2) % 3;
            int ko = (kt + 2) << 5;
            #pragma unroll
            for(int it = 0; it < 2; ++it) GLL4(agA[it] + ko, &Asm[nxt][lda[it]]);
            #pragma unroll
            for(int it = 0; it < 4; ++it) GLL16(bg[it] + ko, &Bsm[nxt][ldb[it]]);
            VMW(12);
        } else if(kt + 1 < 16){
            VMW(6);
        } else {
            VMW(0);
        }
        blockbar();
        short8 af = *(const short8*)&Asm[cur][(wr*16 + lm)*32 + swq];
        #pragma unroll
        for(int j = 0; j < 8; ++j){
            short8 bf = *(const short8*)&Bsm[cur][(wc*128 + j*16 + lm)*32 + swq];
            acc[j] = __builtin_amdgcn_mfma_f32_16x16x32_bf16(af, bf, acc[j], 0, 0, 0);
        }
        __builtin_amdgcn_sched_barrier(0);
        blockbar();
    }
    int row0 = m0 + wr*16 + lq*4;
    float psum[4] = {0.f,0.f,0.f,0.f}, psq[4] = {0.f,0.f,0.f,0.f};
    #pragma unroll
    for(int j = 0; j < 8; ++j){
        int col = wc*128 + j*16 + lm;
        #pragma unroll
        for(int r = 0; r < 4; ++r){
            long idx = (long)(row0 + r)*HID + col;
            float v = s[idx] + acc[j][r];
            acc[j][r] = v;
            s[idx] = v;
            psum[r] += v; psq[r] += v*v;
        }
    }
    #pragma unroll
    for(int mask = 1; mask <= 8; mask <<= 1){
        #pragma unroll
        for(int r = 0; r < 4; ++r){
            psum[r] += __shfl_xor(psum[r], mask);
            psq[r]  += __shfl_xor(psq[r],  mask);
        }
    }
    if(lm == 0){
        #pragma unroll
        for(int r = 0; r < 4; ++r){
            lnred[wr][wc][lq*4 + r][0] = psum[r];
            lnred[wr][wc][lq*4 + r][1] = psq[r];
        }
    }
    __syncthreads();
    float mean[4], rstd[4];
    #pragma unroll
    for(int r = 0; r < 4; ++r){
        float t  = lnred[wr][0][lq*4 + r][0] + lnred[wr][1][lq*4 + r][0];
        float tt = lnred[wr][0][lq*4 + r][1] + lnred[wr][1][lq*4 + r][1];
        mean[r] = t * (1.f/256.f);
        float var = tt * (1.f/256.f) - mean[r]*mean[r];
        rstd[r] = rsqrtf(var + 1e-5f);
    }
    #pragma unroll
    for(int j = 0; j < 8; ++j){
        int col = wc*128 + j*16 + lm;
        float wv = lw[col], bv = lb[col];
        #pragma unroll
        for(int r = 0; r < 4; ++r){
            long idx = (long)(row0 + r)*HID + col;
            xln[idx] = f2bf((acc[j][r] - mean[r]) * rstd[r] * wv + bv);
        }
    }
}

// ---------------- depthwise causal conv1d (k=4) + SiLU; vectorized x8 over d ----------------
__global__ void conv1d_silu_kernel(const u16* __restrict__ xz, const float* __restrict__ w,
                                   const float* __restrict__ bias, u16* __restrict__ xcv){
    int idx = blockIdx.x * 256 + threadIdx.x;    // 1,048,576 threads
    int e = idx * 8;
    int d0 = e & 511;
    long m = e >> 9;
    int l = (int)(m & 4095);
    short8 xrow[4];
    const u16* xp = xz + m*(2*DIN) + d0;
    #pragma unroll
    for(int j = 0; j < 4; ++j){
        int t = l - 3 + j;
        if(t >= 0) xrow[j] = *(const short8*)(xp + (long)(j-3)*(2*DIN));
        else       xrow[j] = (short8){0,0,0,0,0,0,0,0};
    }
    float wv[8][4];
    #pragma unroll
    for(int k = 0; k < 8; k += 2){
        float4 a = *(const float4*)(w + (d0+k)*4);
        float4 b = *(const float4*)(w + (d0+k+1)*4);
        wv[k][0]=a.x; wv[k][1]=a.y; wv[k][2]=a.z; wv[k][3]=a.w;
        wv[k+1][0]=b.x; wv[k+1][1]=b.y; wv[k+1][2]=b.z; wv[k+1][3]=b.w;
    }
    float bz[8];
    {
        float4 a = *(const float4*)(bias + d0);
        float4 b = *(const float4*)(bias + d0 + 4);
        bz[0]=a.x; bz[1]=a.y; bz[2]=a.z; bz[3]=a.w;
        bz[4]=b.x; bz[5]=b.y; bz[6]=b.z; bz[7]=b.w;
    }
    short8 out;
    #pragma unroll
    for(int k = 0; k < 8; ++k){
        float acc = bz[k];
        #pragma unroll
        for(int j = 0; j < 4; ++j)
            acc = fmaf(bf2f((u16)xrow[j][k]), wv[k][j], acc);
        out[k] = (short)f2bf(dsilu(acc));
    }
    *(short8*)(xcv + m*DIN + d0) = out;
}

// ---------------- fused scan: phase1 (chunk states) + combine + phase3 (replay) ----------------
// grid (NCHUNK=64, 2, BB=4) = 512 blocks, 256 thr, 40KB LDS -> all co-resident.
__global__ __launch_bounds__(256, 2) void scan_fused_kernel(
        const u16* __restrict__ xcvb, const u16* __restrict__ dvin,
        const float* __restrict__ xdbl32, const float* __restrict__ Alog,
        const float* __restrict__ Dp, const u16* __restrict__ xz,
        float* __restrict__ aprod, float* __restrict__ hend,
        float* __restrict__ hinit, u16* __restrict__ yout,
        unsigned* __restrict__ bar){
    __shared__ u16 xls[LCH*256];            // 32 KB: xcv chunk [t][256 d]
    __shared__ float bm[LCH][16], cm[LCH][16];  // 8 KB
    int tid = threadIdx.x;
    int c = blockIdx.x, dh = blockIdx.y, b = blockIdx.z;
    int d = dh*256 + tid;
    // stage bm/cm from xdbl
    {
        int t = tid >> 4, n = tid & 15;
        #pragma unroll
        for(int it = 0; it < 4; ++it){
            long p = ((long)(b*LSEQ + c*LCH + t + it*16))*32;
            bm[t + it*16][n] = xdbl32[p + n];
            cm[t + it*16][n] = xdbl32[p + 16 + n];
        }
    }
    // stage xcv chunk -> LDS (GLL16, linear dest)
    #pragma unroll
    for(int it = 0; it < 8; ++it){
        int e = it*256 + tid;               // 2048 x 16B chunks
        int tt = e >> 5, q = e & 31;
        long g = ((long)(b*LSEQ + c*LCH + tt))*DIN + dh*256 + q*8;
        GLL16(xcvb + g, &xls[e*8]);
    }
    VMW(0);
    __syncthreads();

    float An[16];
    #pragma unroll
    for(int n = 0; n < 16; ++n)
        An[n] = -__expf(Alog[d*16 + n]);
    float An0 = An[0];
    bool structural = true;
    #pragma unroll
    for(int n = 0; n < 16; ++n)
        structural = structural && (fabsf(An[n] - (float)(n+1)*An0) <= 1e-3f*(float)(n+1));
    long base = ((long)(b*LSEQ + c*LCH))*DIN + d;
    long ob = (((long)(b*NCHUNK + c))*DIN + d)*16;

    // ---- phase 1 ----
    if(structural){
        f32x2 h2[8];
        #pragma unroll
        for(int i = 0; i < 8; ++i) h2[i] = (f32x2){0.f, 0.f};
        float sumdv = 0.f;
        float dv_n = bf2f(dvin[base]);
        for(int t = 0; t < LCH; ++t){
            float dv = dv_n;
            if(t + 1 < LCH) dv_n = bf2f(dvin[base + (long)(t+1)*DIN]);
            float xv = bf2f(xls[t*256 + tid]);
            sumdv += dv;
            float db = dv * xv;
            float r1 = __expf(dv * An0);
            float r2 = r1 * r1;
            f32x2 rr = {r2, r2};
            f32x2 e2[8];
            e2[0] = (f32x2){r1, r2};
            #pragma unroll
            for(int i = 1; i < 8; ++i) e2[i] = e2[i-1] * rr;
            f32x2 db2 = {db, db};
            const f32x2* b2 = (const f32x2*)&bm[t][0];
            #pragma unroll
            for(int i = 0; i < 8; ++i) h2[i] = e2[i]*h2[i] + db2*b2[i];
        }
        float R = __expf(An0 * sumdv);
        float Rp = R;
        const float* hp = (const float*)h2;
        #pragma unroll
        for(int n = 0; n < 16; ++n){
            aprod[ob+n] = Rp; Rp *= R;
            hend[ob+n] = hp[n];
        }
    } else {
        float h[16], ap[16];
        #pragma unroll
        for(int n = 0; n < 16; ++n){ h[n] = 0.f; ap[n] = 1.f; }
        for(int t = 0; t < LCH; ++t){
            float dv = bf2f(dvin[base + (long)t*DIN]);
            float db = dv * bf2f(xls[t*256 + tid]);
            #pragma unroll
            for(int n = 0; n < 16; ++n){
                float e = __expf(dv * An[n]);
                ap[n] *= e;
                h[n] = fmaf(e, h[n], db * bm[t][n]);
            }
        }
        #pragma unroll
        for(int n = 0; n < 16; ++n){ aprod[ob+n] = ap[n]; hend[ob+n] = h[n]; }
    }

    gridbar(bar + 0, 512);

    // ---- phase 2: sequential combine over chunks (32768 sequences) ----
    {
        int bid = (b*2 + dh)*NCHUNK + c;
        int gtid = bid*256 + tid;
        if(gtid < 32768){
            int n2 = gtid & 15, d2 = (gtid >> 4) & 511, b2 = gtid >> 13;
            const long stride = (long)DIN * 16;
            long p0 = (((long)(b2*NCHUNK))*DIN + d2)*16 + n2;
            float h = 0.f;
            for(int cc = 0; cc < NCHUNK; cc += 8){
                float a[8], e[8];
                #pragma unroll
                for(int j = 0; j < 8; ++j){
                    long p = p0 + (long)(cc + j)*stride;
                    a[j] = aprod[p]; e[j] = hend[p];
                }
                #pragma unroll
                for(int j = 0; j < 8; ++j){
                    hinit[p0 + (long)(cc + j)*stride] = h;
                    h = fmaf(a[j], h, e[j]);
                }
            }
        }
    }

    gridbar(bar + 1, 512);

    // ---- phase 3: replay with carried-in state + epilogue ----
    long hb = ob;
    float Dv = Dp[d];
    long zbase = ((long)(b*LSEQ + c*LCH))*(2*DIN) + DIN + d;
    if(structural){
        f32x2 h2[8];
        {
            const f32x2* hi = (const f32x2*)&hinit[hb];
            #pragma unroll
            for(int i = 0; i < 8; ++i) h2[i] = hi[i];
        }
        float z_n  = bf2f(xz[zbase]);
        float dv_n = bf2f(dvin[base]);
        for(int t = 0; t < LCH; ++t){
            float z = z_n, dv = dv_n;
            if(t + 1 < LCH){
                z_n  = bf2f(xz[zbase + (long)(t+1)*(2*DIN)]);
                dv_n = bf2f(dvin[base + (long)(t+1)*DIN]);
            }
            float xv = bf2f(xls[t*256 + tid]);
            float db = dv * xv;
            float r1 = __expf(dv * An0);
            float r2 = r1 * r1;
            f32x2 rr = {r2, r2};
            f32x2 e2[8];
            e2[0] = (f32x2){r1, r2};
            #pragma unroll
            for(int i = 1; i < 8; ++i) e2[i] = e2[i-1] * rr;
            f32x2 db2 = {db, db};
            const f32x2* b2 = (const f32x2*)&bm[t][0];
            const f32x2* c2 = (const f32x2*)&cm[t][0];
            f32x2 y2 = {0.f, 0.f};
            #pragma unroll
            for(int i = 0; i < 8; ++i){
                h2[i] = e2[i]*h2[i] + db2*b2[i];
                y2 = y2 + h2[i]*c2[i];
            }
            float y = y2[0] + y2[1];
            y = fmaf(xv, Dv, y);
            yout[base + (long)t*DIN] = f2bf(y * dsilu(z));
        }
    } else {
        float h[16];
        #pragma unroll
        for(int n = 0; n < 16; ++n) h[n] = hinit[hb + n];
        for(int t = 0; t < LCH; ++t){
            float dv = bf2f(dvin[base + (long)t*DIN]);
            float xv = bf2f(xls[t*256 + tid]);
            float db = dv * xv;
            float y = 0.f;
            #pragma unroll
            for(int n = 0; n < 16; ++n){
                float e = __expf(dv * An[n]);
                h[n] = fmaf(e, h[n], db * bm[t][n]);
                y = fmaf(h[n], cm[t][n], y);
            }
            y = fmaf(xv, Dv, y);
            float z = bf2f(xz[zbase + (long)t*(2*DIN)]);
            yout[base + (long)t*DIN] = f2bf(y * dsilu(z));
        }
    }
}

// ---------------- final copy ----------------
__global__ void copyout_kernel(const float* __restrict__ s, float* __restrict__ out, int out_size){
    int idx = blockIdx.x * 256 + threadIdx.x;
    if(idx >= out_size) return;
    out[idx] = (idx < BB*LSEQ*HID) ? s[idx] : 64.0f;
}

extern "C" void kernel_launch(void* const* d_in, const int* in_sizes, int n_in,
                              void* d_out, int out_size, void* d_ws, size_t ws_size,
                              hipStream_t stream){
    const float* x        = (const float*)d_in[0];
    const float* conv1_w  = (const float*)d_in[1];
    const float* conv1_b  = (const float*)d_in[2];
    const float* gn1_w    = (const float*)d_in[3];
    const float* gn1_b    = (const float*)d_in[4];
    const float* conv2_w  = (const float*)d_in[5];
    const float* conv2_b  = (const float*)d_in[6];
    const float* gn2_w    = (const float*)d_in[7];
    const float* gn2_b    = (const float*)d_in[8];
    const float* ln_w     = (const float*)d_in[9];
    const float* ln_b     = (const float*)d_in[10];
    const float* in_proj  = (const float*)d_in[11];
    const float* c1d_w    = (const float*)d_in[12];
    const float* c1d_b    = (const float*)d_in[13];
    const float* x_proj   = (const float*)d_in[14];
    const float* dt_w     = (const float*)d_in[15];
    const float* dt_b     = (const float*)d_in[16];
    const float* A_log    = (const float*)d_in[17];
    const float* Dvec     = (const float*)d_in[18];
    const float* out_proj = (const float*)d_in[19];

    float* ws = (float*)d_ws;
    float* s      = ws;                       // 4,194,304 f
    u16*   xz_bf  = (u16*)(ws + 4194304);     // 16,777,216 u16 (8,388,608 f)
    float* y1     = ws + 4194304;             // alias: y1 fp32 (stem only)
    u16*   xt     = (u16*)(ws + 12582912);    // 8,652,800 u16 (4,326,400 f)
    u16*   xcv_bf = (u16*)(ws + 16909312);    // 8,388,608 u16 (4,194,304 f)
    float* y2t    = ws + 16909312;            // alias: y2t fp32 (stem only)
    u16*   xln_bf = (u16*)(ws + 21103616);    // 4,194,304 u16 (2,097,152 f)
    float* xdbl   = ws + 23200768;            // 524,288 f (16384 x 32)
    unsigned* bars = (unsigned*)(ws + 23725056); // 16 u (slack in xdbl slot)
    float* aprod  = ws + 23987200;            // 2,097,152 f used (slot 4,194,304 f)
    float* hendb  = ws + 28181504;            // 2,097,152 f used
    u16*   y_bf   = (u16*)aprod;              // alias: y (8,388,608 u16) fits in aprod slot
    float* hinit  = ws + 32375808;            // 2,097,152 f used
    float* stats  = ws + 36570112;            // 64 f
    u16*   ipw_bf = (u16*)(ws + 36570176);    // 1,048,576 u16 (524,288 f)
    u16*   opw_bf = ipw_bf + 1048576;         //   524,288 u16 (262,144 f)
    u16*   c2w_bf = opw_bf + 524288;          //   294,912 u16 (147,456 f)
    u16*   dv_bf  = (u16*)(ws + 37635200);    // 8,388,608 u16 (4,194,304 f)
    u16*   wcomb  = (u16*)(ws + 41829504);    // 1,310,720 u16 (655,360 f) -> end 42,484,864 f

    // ---- weight prep ----
    bar_init_kernel<<<1, 16, 0, stream>>>(bars);
    f2bf_kernel<<<4096, 256, 0, stream>>>(in_proj, ipw_bf);
    f2bf_kernel<<<2048, 256, 0, stream>>>(out_proj, opw_bf);
    c2w_prep_kernel<<<1152, 256, 0, stream>>>(conv2_w, c2w_bf);
    wdt_prep_kernel<<<5120, 256, 0, stream>>>(x_proj, dt_w, wcomb);

    // ---- stem ----
    conv1_kernel<<<dim3(128,4), 256, 0, stream>>>(x, conv1_w, conv1_b, y1);
    zero_stats_kernel<<<1, 64, 0, stream>>>(stats);
    gn_stats_kernel<<<512, 256, 0, stream>>>(y1, stats, 16*H1*W1);
    xt_border_kernel<<<516, 256, 0, stream>>>((unsigned*)xt);
    gn1_transform_kernel<<<dim3(4,4,512), dim3(32,8), 0, stream>>>(y1, stats, gn1_w, gn1_b, xt);
    conv2gemm_bf16_kernel<<<dim3(256,2), 256, 0, stream>>>(xt, c2w_bf, conv2_b, y2t);
    zero_stats_kernel<<<1, 64, 0, stream>>>(stats);
    gn2t_stats_kernel<<<dim3(64,4), 256, 0, stream>>>(y2t, stats);
    gn2t_apply_ln_kernel<<<16384, 256, 0, stream>>>(y2t, stats, gn2_w, gn2_b,
                                                    ln_w, ln_b, s, xln_bf);

    // ---- 4 mamba layers ----
    for(int layer = 0; layer < NL; ++layer){
        const float* cw  = c1d_w + (long)layer*DIN*4;
        const float* cb  = c1d_b + (long)layer*DIN;
        const float* dpb = dt_b  + (long)layer*DIN;
        const float* Al  = A_log + (long)layer*DIN*DST;
        const float* Dl  = Dvec  + (long)layer*DIN;
        int lnext = (layer + 1) & 3;   // ln params for the NEXT layer's input

        gemm_bf16_kernel<<<dim3(128,8), 256, 0, stream>>>(
            xln_bf, ipw_bf + (long)layer*1024*256, xz_bf, HID, 2*DIN, 2*DIN, 2);
        conv1d_silu_kernel<<<4096, 256, 0, stream>>>(xz_bf, cw, cb, xcv_bf);
        gemm_dtbc_kernel<<<dim3(128,5), 256, 0, stream>>>(
            xcv_bf, wcomb + (long)layer*640*512, dpb, dv_bf, xdbl);
        scan_fused_kernel<<<dim3(NCHUNK,2,BB), 256, 0, stream>>>(
            xcv_bf, dv_bf, xdbl, Al, Dl, xz_bf, aprod, hendb, hinit, y_bf,
            bars + layer*2);
        gemm_out_ln_kernel<<<512, 256, 0, stream>>>(
            y_bf, opw_bf + (long)layer*256*512, s, xln_bf,
            ln_w + lnext*HID, ln_b + lnext*HID);
    }

    copyout_kernel<<<(out_size + 255)/256, 256, 0, stream>>>(s, (float*)d_out, out_size);
}

// Round 5
// 1388.340 us; speedup vs baseline: 1.7113x; 1.7113x over previous
//
#include <hip/hip_runtime.h>
#include <math.h>

#define BB 4
#define C1 128
#define H1 128
#define W1 128
#define C2 256
#define H2 64
#define W2 64
#define LSEQ 4096
#define HID 256
#define DIN 512
#define DST 16
#define DTR 16
#define NL 4
#define NCHUNK 64
#define LCH 64

typedef unsigned short u16;
using short8 = __attribute__((ext_vector_type(8))) short;
using f32x4  = __attribute__((ext_vector_type(4))) float;
using f32x2  = __attribute__((ext_vector_type(2))) float;

static __device__ __forceinline__ float dsilu(float x){
    return x / (1.0f + __expf(-x));
}
static __device__ __forceinline__ u16 f2bf(float f){
    unsigned u = __float_as_uint(f);
    u += 0x7FFF + ((u >> 16) & 1);
    return (u16)(u >> 16);
}
static __device__ __forceinline__ float bf2f(u16 v){
    return __uint_as_float(((unsigned)v) << 16);
}

#define GLL16(g, l) __builtin_amdgcn_global_load_lds( \
    (const __attribute__((address_space(1))) void*)(g), \
    (__attribute__((address_space(3))) void*)(l), 16, 0, 0)
#define GLL4(g, l) __builtin_amdgcn_global_load_lds( \
    (const __attribute__((address_space(1))) void*)(g), \
    (__attribute__((address_space(3))) void*)(l), 4, 0, 0)

#define VMW(n) asm volatile("s_waitcnt vmcnt(" #n ")" ::: "memory")

static __device__ __forceinline__ void blockbar(){
    asm volatile("" ::: "memory");
    __builtin_amdgcn_s_barrier();
    asm volatile("" ::: "memory");
}

// ---------------- mega prep: bf16 weight casts + wcomb + xt border + stats zero ----------------
__global__ void prep_kernel(const float* __restrict__ in_proj, const float* __restrict__ out_proj,
                            const float* __restrict__ conv2_w, const float* __restrict__ xpw,
                            const float* __restrict__ dpw,
                            u16* __restrict__ ipw_bf, u16* __restrict__ opw_bf,
                            u16* __restrict__ c2w_bf, u16* __restrict__ wcomb,
                            unsigned* __restrict__ xt, float* __restrict__ stats){
    int bx = blockIdx.x, tid = threadIdx.x;
    if(bx < 4096){
        int idx = bx*256 + tid;
        ipw_bf[idx] = f2bf(in_proj[idx]);
        return;
    }
    bx -= 4096;
    if(bx < 2048){
        int idx = bx*256 + tid;
        opw_bf[idx] = f2bf(out_proj[idx]);
        return;
    }
    bx -= 2048;
    if(bx < 1152){
        int idx = bx*256 + tid;      // 294912
        int ci = idx & 127, p = (idx >> 7) % 9, co = idx / (9*128);
        int kh = p / 3, kw = p - 3*kh;
        c2w_bf[idx] = f2bf(conv2_w[((co*128 + ci)*3 + kh)*3 + kw]);
        return;
    }
    bx -= 1152;
    if(bx < 5120){
        int idx = bx*256 + tid;      // 1,310,720
        int k = idx & 511;
        int n = (idx >> 9) % 640;
        int layer = idx / (640*512);
        u16 val = 0;
        if(n < 512){
            const float* dp = dpw + ((long)layer*512 + n)*16;
            const float* xp = xpw + (long)layer*48*512 + k;
            float acc = 0.f;
            #pragma unroll
            for(int r = 0; r < 16; ++r) acc = fmaf(dp[r], xp[(long)r*512], acc);
            val = f2bf(acc);
        } else if(n < 544){
            int row = n - 512 + 16;
            val = f2bf(xpw[((long)layer*48 + row)*512 + k]);
        }
        wcomb[((long)layer*640 + n)*512 + k] = val;
        return;
    }
    bx -= 5120;
    if(bx < 516){
        int idx = bx*256 + tid;      // 132,096
        int c2 = idx & 63;
        int cell = (idx >> 6) % 516;
        int b = idx / (516*64);
        int ih, iw;
        if(cell < 130){ ih = 0; iw = cell; }
        else if(cell < 260){ ih = 129; iw = cell - 130; }
        else if(cell < 388){ iw = 0; ih = cell - 259; }
        else { iw = 129; ih = cell - 387; }
        xt[((long)(b*130 + ih)*130 + iw)*64 + c2] = 0;
        return;
    }
    // last block: zero stats (GN1: 0..63, GN2: 64..127)
    if(tid < 128) stats[tid] = 0.f;
}

// ---------------- conv1 via LDS row staging + fused GN1 stats ----------------
__global__ __launch_bounds__(256) void conv1_kernel(
        const float* __restrict__ x, const float* __restrict__ w,
        const float* __restrict__ bias, float* __restrict__ y,
        float* __restrict__ stats){
    __shared__ float xs[9][260];
    int oh = blockIdx.x, b = blockIdx.y;
    int tid = threadIdx.x;
    #pragma unroll
    for(int r = 0; r < 9; ++r){
        int ci = r / 3, kh = r - 3*ci;
        int ih = 2*oh - 1 + kh;
        float v = 0.f;
        if(ih >= 0) v = x[((b*3 + ci)*256 + ih)*256 + tid];
        xs[r][tid + 1] = v;
        if(tid == 0) xs[r][0] = 0.f;
    }
    __syncthreads();
    int co = tid >> 1, h = tid & 1;
    float wr[27];
    #pragma unroll
    for(int j = 0; j < 27; ++j) wr[j] = w[co*27 + j];
    float bz = bias[co];
    long obase = ((long)((b*128 + co)*128 + oh))*128 + h*64;
    float s = 0.f, ss = 0.f;
    #pragma unroll 4
    for(int i = 0; i < 64; ++i){
        int iw0 = 2*(h*64 + i);
        float acc = bz;
        #pragma unroll
        for(int r = 0; r < 9; ++r){
            acc = fmaf(xs[r][iw0+0], wr[r*3+0], acc);
            acc = fmaf(xs[r][iw0+1], wr[r*3+1], acc);
            acc = fmaf(xs[r][iw0+2], wr[r*3+2], acc);
        }
        y[obase + i] = acc;
        s += acc; ss += acc*acc;
    }
    // GN1 group = co>>4 = tid>>5: 32 consecutive threads per group
    #pragma unroll
    for(int off = 16; off; off >>= 1){
        s  += __shfl_down(s,  off);
        ss += __shfl_down(ss, off);
    }
    if((tid & 31) == 0){
        int g = b*8 + (tid >> 5);
        atomicAdd(&stats[g], s);
        atomicAdd(&stats[32 + g], ss);
    }
}

// ---------------- GN1 apply + SiLU + NCHW -> padded channels-last bf16 ----------------
__global__ void gn1_transform_kernel(const float* __restrict__ y1, const float* __restrict__ stats,
                                     const float* __restrict__ w, const float* __restrict__ bias,
                                     u16* __restrict__ xt){
    __shared__ float tile[32][33];
    int b = blockIdx.z >> 7, ih = blockIdx.z & 127;
    int c0 = blockIdx.y * 32, w0 = blockIdx.x * 32;
    int tx = threadIdx.x, ty = threadIdx.y;   // 32 x 8
    const float cnt = 16.f * 128.f * 128.f;
    #pragma unroll
    for(int i = 0; i < 4; ++i){
        int ci = c0 + ty + i*8;
        int g = b*8 + (ci >> 4);
        float mean = stats[g] / cnt;
        float var  = stats[32+g] / cnt - mean*mean;
        float rstd = rsqrtf(var + 1e-5f);
        float v = y1[(((long)(b*C1 + ci))*H1 + ih)*W1 + w0 + tx];
        tile[ty + i*8][tx] = dsilu((v - mean) * rstd * w[ci] + bias[ci]);
    }
    __syncthreads();
    #pragma unroll
    for(int i = 0; i < 4; ++i){
        int iwl = ty + i*8;
        xt[((long)(b*130 + ih + 1)*130 + (w0 + iwl + 1))*128 + c0 + tx] = f2bf(tile[tx][iwl]);
    }
}

// ---------------- conv2 implicit GEMM (tile 64x128, 3-stage) + fused GN2 stats ----------------
__global__ __launch_bounds__(256) void conv2gemm_bf16_kernel(
        const u16* __restrict__ xt, const u16* __restrict__ w2,
        const float* __restrict__ bias, float* __restrict__ y2t,
        float* __restrict__ stats){
    __shared__ u16 Asm[3][64*32];    // 12 KB
    __shared__ u16 Bsm[3][128*32];   // 24 KB
    int m0 = blockIdx.x * 64, n0 = blockIdx.y * 128;
    int tid = threadIdx.x;
    long abase;
    {
        int r = tid >> 2;
        int kq = ((tid & 3) ^ ((r >> 1) & 3)) * 8;
        int m = m0 + r;
        int b = m >> 12, oh = (m >> 6) & 63, ow = m & 63;
        abase = ((long)(b*130 + 2*oh)*130 + 2*ow)*128 + kq;
    }
    int lda = tid*8;
    const u16* bbase[2]; int ldb[2];
    #pragma unroll
    for(int it = 0; it < 2; ++it){
        int c = it*256 + tid;
        int r = c >> 2;
        int kq = ((c & 3) ^ ((r >> 1) & 3)) * 8;
        bbase[it] = w2 + (long)(n0 + r)*1152 + kq;
        ldb[it] = c*8;
    }
    int wave = tid >> 6, lane = tid & 63;
    int wr = wave >> 1, wc = wave & 1;
    int lm = lane & 15, lq = lane >> 4;
    int swq = (lq ^ ((lm >> 1) & 3)) * 8;
    f32x4 acc[2][4] = {};
    #pragma unroll
    for(int pt = 0; pt < 2; ++pt){
        int p = pt >> 2, cs = pt & 3;
        int kh = p / 3, kw = p - 3*kh;
        int ao = (kh*130 + kw)*128 + cs*32;
        GLL16(xt + abase + ao, &Asm[pt][lda]);
        #pragma unroll
        for(int it = 0; it < 2; ++it)
            GLL16(bbase[it] + pt*32, &Bsm[pt][ldb[it]]);
    }
    for(int kk = 0; kk < 36; ++kk){
        int cur = kk % 3;
        if(kk + 2 < 36){
            int k2 = kk + 2;
            int nxt = (kk + 2) % 3;
            int p = k2 >> 2, cs = k2 & 3;
            int kh = p / 3, kw = p - 3*kh;
            int ao = (kh*130 + kw)*128 + cs*32;
            GLL16(xt + abase + ao, &Asm[nxt][lda]);
            #pragma unroll
            for(int it = 0; it < 2; ++it)
                GLL16(bbase[it] + k2*32, &Bsm[nxt][ldb[it]]);
            VMW(6);
        } else if(kk + 1 < 36){
            VMW(3);
        } else {
            VMW(0);
        }
        blockbar();
        short8 af[2], bf[4];
        #pragma unroll
        for(int i = 0; i < 2; ++i)
            af[i] = *(const short8*)&Asm[cur][(wr*32 + i*16 + lm)*32 + swq];
        #pragma unroll
        for(int j = 0; j < 4; ++j)
            bf[j] = *(const short8*)&Bsm[cur][(wc*64 + j*16 + lm)*32 + swq];
        #pragma unroll
        for(int i = 0; i < 2; ++i)
            #pragma unroll
            for(int j = 0; j < 4; ++j)
                acc[i][j] = __builtin_amdgcn_mfma_f32_16x16x32_bf16(af[i], bf[j], acc[i][j], 0, 0, 0);
        __builtin_amdgcn_sched_barrier(0);
        blockbar();
    }
    // epilogue + GN2 stats (group = col>>5; wc wave-uniform -> 2 groups/wave)
    float gs0 = 0.f, gss0 = 0.f, gs1 = 0.f, gss1 = 0.f;
    #pragma unroll
    for(int i = 0; i < 2; ++i){
        long row = m0 + wr*32 + i*16 + lq*4;
        #pragma unroll
        for(int j = 0; j < 4; ++j){
            int col = n0 + wc*64 + j*16 + lm;
            float bz = bias[col];
            #pragma unroll
            for(int r = 0; r < 4; ++r){
                float v = acc[i][j][r] + bz;
                y2t[(row + r)*256L + col] = v;
                if(j < 2){ gs0 += v; gss0 += v*v; } else { gs1 += v; gss1 += v*v; }
            }
        }
    }
    #pragma unroll
    for(int off = 32; off; off >>= 1){
        gs0 += __shfl_down(gs0, off); gss0 += __shfl_down(gss0, off);
        gs1 += __shfl_down(gs1, off); gss1 += __shfl_down(gss1, off);
    }
    if(lane == 0){
        int b = m0 >> 12;
        int gb = b*8 + (n0 >> 5) + wc*2;
        atomicAdd(&stats[64 + gb],     gs0);
        atomicAdd(&stats[96 + gb],     gss0);
        atomicAdd(&stats[64 + gb + 1], gs1);
        atomicAdd(&stats[96 + gb + 1], gss1);
    }
}

// ---------------- GN2 apply + SiLU -> s, fused LayerNorm(layer 0) -> xln_bf ----------------
__global__ void gn2t_apply_ln_kernel(const float* __restrict__ y2t, const float* __restrict__ stats,
                                     const float* __restrict__ gw, const float* __restrict__ gb,
                                     const float* __restrict__ lw, const float* __restrict__ lb,
                                     float* __restrict__ s, u16* __restrict__ xln){
    long row = blockIdx.x;                        // 16384 rows
    int c = threadIdx.x;                          // 256
    int b = (int)(row >> 12);
    int g = b*8 + (c >> 5);
    const float cnt = 32.f * (float)LSEQ;
    float mean = stats[64+g] / cnt;
    float var  = stats[96+g] / cnt - mean*mean;
    float rstd = rsqrtf(var + 1e-5f);
    float v = dsilu((y2t[row*HID + c] - mean) * rstd * gw[c] + gb[c]);
    s[row*HID + c] = v;
    float sm = v, sq = v*v;
    #pragma unroll
    for(int off = 32; off; off >>= 1){
        sm += __shfl_down(sm, off);
        sq += __shfl_down(sq, off);
    }
    __shared__ float pa[4], pb[4], res[2];
    int wid = c >> 6, lane = c & 63;
    if(lane == 0){ pa[wid] = sm; pb[wid] = sq; }
    __syncthreads();
    if(c == 0){
        float t  = pa[0]+pa[1]+pa[2]+pa[3];
        float tt = pb[0]+pb[1]+pb[2]+pb[3];
        float m2 = t / 256.f;
        float v2 = tt / 256.f - m2*m2;
        res[0] = m2; res[1] = rsqrtf(v2 + 1e-5f);
    }
    __syncthreads();
    xln[row*HID + c] = f2bf((v - res[0]) * res[1] * lw[c] + lb[c]);
}

// ---------------- in_proj GEMM + fused causal conv1d(k=4)+SiLU epilogue ----------------
// A = xln [16384][256], B = ipw [1024][256]. n0<512: conv+silu -> xcv; n0>=512: z -> xz.
__global__ __launch_bounds__(256) void gemm_inproj_conv_kernel(
        const u16* __restrict__ A, const u16* __restrict__ B,
        u16* __restrict__ xz, u16* __restrict__ xcv,
        const float* __restrict__ cw, const float* __restrict__ cb){
    __shared__ u16 smem[24576];   // Asm[3][4096] | Bsm[3][4096]; reused as xcs[131][128]
    u16* Abuf = smem;
    u16* Bbuf = smem + 12288;
    int m0 = blockIdx.x * 128, n0 = blockIdx.y * 128;
    int tid = threadIdx.x;
    int wave = tid >> 6, lane = tid & 63;
    int wr = wave >> 1, wc = wave & 1;
    int lm = lane & 15, lq = lane >> 4;
    int swq = (lq ^ ((lm >> 1) & 3)) * 8;
    const u16* ag[2]; const u16* bg[2]; int ldst[2];
    #pragma unroll
    for(int it = 0; it < 2; ++it){
        int c = it*256 + tid;
        int r = c >> 2;
        int kq = ((c & 3) ^ ((r >> 1) & 3)) * 8;
        ag[it] = A + (long)(m0 + r)*256 + kq;
        bg[it] = B + (long)(n0 + r)*256 + kq;
        ldst[it] = c*8;
    }
    f32x4 acc[4][4] = {};
    #pragma unroll
    for(int pt = 0; pt < 2; ++pt){
        int ko = pt << 5;
        #pragma unroll
        for(int it = 0; it < 2; ++it){
            GLL16(ag[it] + ko, &Abuf[pt*4096 + ldst[it]]);
            GLL16(bg[it] + ko, &Bbuf[pt*4096 + ldst[it]]);
        }
    }
    for(int kt = 0; kt < 8; ++kt){
        int cur = kt % 3;
        if(kt + 2 < 8){
            int nxt = (kt + 2) % 3;
            int ko = (kt + 2) << 5;
            #pragma unroll
            for(int it = 0; it < 2; ++it){
                GLL16(ag[it] + ko, &Abuf[nxt*4096 + ldst[it]]);
                GLL16(bg[it] + ko, &Bbuf[nxt*4096 + ldst[it]]);
            }
            VMW(8);
        } else if(kt + 1 < 8){
            VMW(4);
        } else {
            VMW(0);
        }
        blockbar();
        short8 af[4], bf[4];
        #pragma unroll
        for(int i = 0; i < 4; ++i){
            af[i] = *(const short8*)&Abuf[cur*4096 + (wr*64 + i*16 + lm)*32 + swq];
            bf[i] = *(const short8*)&Bbuf[cur*4096 + (wc*64 + i*16 + lm)*32 + swq];
        }
        #pragma unroll
        for(int i = 0; i < 4; ++i)
            #pragma unroll
            for(int j = 0; j < 4; ++j)
                acc[i][j] = __builtin_amdgcn_mfma_f32_16x16x32_bf16(af[i], bf[j], acc[i][j], 0, 0, 0);
        __builtin_amdgcn_sched_barrier(0);
        blockbar();
    }
    if(n0 >= 512){
        // z half -> xz bf16
        #pragma unroll
        for(int i = 0; i < 4; ++i){
            long row = m0 + wr*64 + i*16 + lq*4;
            #pragma unroll
            for(int j = 0; j < 4; ++j){
                int col = n0 + wc*64 + j*16 + lm;
                #pragma unroll
                for(int r = 0; r < 4; ++r)
                    xz[(row + r)*1024L + col] = f2bf(acc[i][j][r]);
            }
        }
        return;
    }
    // ---- conv epilogue (smem is dead: all LDS reads completed before last barrier) ----
    u16* xcs = smem;   // [131][128]: rows 0..2 = halo (m0-3..m0-1), rows 3..130 = main
    bool first = ((m0 & 4095) == 0);
    for(int jj = tid; jj < 384; jj += 256){
        int hr = jj >> 7, cc = jj & 127;
        u16 val = 0;
        if(!first){
            const u16* ar = A + (long)(m0 - 3 + hr)*256;
            const u16* br = B + (long)(n0 + cc)*256;
            float a2 = 0.f;
            #pragma unroll 4
            for(int k = 0; k < 256; k += 8){
                short8 av = *(const short8*)(ar + k);
                short8 bv = *(const short8*)(br + k);
                #pragma unroll
                for(int q = 0; q < 8; ++q)
                    a2 = fmaf(bf2f((u16)av[q]), bf2f((u16)bv[q]), a2);
            }
            val = f2bf(a2);
        }
        xcs[hr*128 + cc] = val;
    }
    #pragma unroll
    for(int i = 0; i < 4; ++i){
        int rl = wr*64 + i*16 + lq*4;
        #pragma unroll
        for(int j = 0; j < 4; ++j){
            int cl = wc*64 + j*16 + lm;
            #pragma unroll
            for(int r = 0; r < 4; ++r)
                xcs[(3 + rl + r)*128 + cl] = f2bf(acc[i][j][r]);
        }
    }
    __syncthreads();
    {
        int c = tid & 127, h = tid >> 7;
        float4 w4 = *(const float4*)(cw + (n0 + c)*4);
        float bz = cb[n0 + c];
        int r0 = h*64;
        float v0 = bf2f(xcs[(r0+0)*128 + c]);
        float v1 = bf2f(xcs[(r0+1)*128 + c]);
        float v2 = bf2f(xcs[(r0+2)*128 + c]);
        long gbase = (long)(m0 + r0)*512 + n0 + c;
        for(int i2 = 0; i2 < 64; ++i2){
            float v3 = bf2f(xcs[(r0+3+i2)*128 + c]);
            float a2 = fmaf(v0, w4.x, bz);
            a2 = fmaf(v1, w4.y, a2);
            a2 = fmaf(v2, w4.z, a2);
            a2 = fmaf(v3, w4.w, a2);
            xcv[gbase + (long)i2*512] = f2bf(dsilu(a2));
            v0 = v1; v1 = v2; v2 = v3;
        }
    }
}

// ---------------- fused dt-proj (softplus) + x_proj B/C GEMM (3-stage) ----------------
__global__ __launch_bounds__(256) void gemm_dtbc_kernel(
        const u16* __restrict__ A, const u16* __restrict__ B,
        const float* __restrict__ dpb, u16* __restrict__ dv,
        float* __restrict__ xdbl32){
    __shared__ u16 Asm[3][128*32];
    __shared__ u16 Bsm[3][128*32];
    int m0 = blockIdx.x * 128, n0 = blockIdx.y * 128;
    int tid = threadIdx.x;
    int wave = tid >> 6, lane = tid & 63;
    int wr = wave >> 1, wc = wave & 1;
    int lm = lane & 15, lq = lane >> 4;
    int swq = (lq ^ ((lm >> 1) & 3)) * 8;
    int jlim = (n0 < 512) ? 4 : ((wc == 0) ? 2 : 0);
    const u16* ag[2]; const u16* bg[2]; int ldst[2];
    #pragma unroll
    for(int it = 0; it < 2; ++it){
        int c = it*256 + tid;
        int r = c >> 2;
        int kq = ((c & 3) ^ ((r >> 1) & 3)) * 8;
        ag[it] = A + (long)(m0 + r)*512 + kq;
        bg[it] = B + (long)(n0 + r)*512 + kq;
        ldst[it] = c*8;
    }
    f32x4 acc[4][4] = {};
    #pragma unroll
    for(int pt = 0; pt < 2; ++pt){
        int ko = pt << 5;
        #pragma unroll
        for(int it = 0; it < 2; ++it){
            GLL16(ag[it] + ko, &Asm[pt][ldst[it]]);
            GLL16(bg[it] + ko, &Bsm[pt][ldst[it]]);
        }
    }
    for(int kt = 0; kt < 16; ++kt){
        int cur = kt % 3;
        if(kt + 2 < 16){
            int nxt = (kt + 2) % 3;
            int ko = (kt + 2) << 5;
            #pragma unroll
            for(int it = 0; it < 2; ++it){
                GLL16(ag[it] + ko, &Asm[nxt][ldst[it]]);
                GLL16(bg[it] + ko, &Bsm[nxt][ldst[it]]);
            }
            VMW(8);
        } else if(kt + 1 < 16){
            VMW(4);
        } else {
            VMW(0);
        }
        blockbar();
        short8 af[4];
        #pragma unroll
        for(int i = 0; i < 4; ++i)
            af[i] = *(const short8*)&Asm[cur][(wr*64 + i*16 + lm)*32 + swq];
        for(int j = 0; j < jlim; ++j){
            short8 bf = *(const short8*)&Bsm[cur][(wc*64 + j*16 + lm)*32 + swq];
            #pragma unroll
            for(int i = 0; i < 4; ++i)
                acc[i][j] = __builtin_amdgcn_mfma_f32_16x16x32_bf16(af[i], bf, acc[i][j], 0, 0, 0);
        }
        __builtin_amdgcn_sched_barrier(0);
        blockbar();
    }
    if(n0 < 512){
        #pragma unroll
        for(int i = 0; i < 4; ++i){
            long row = m0 + wr*64 + i*16 + lq*4;
            #pragma unroll
            for(int j = 0; j < 4; ++j){
                int col = n0 + wc*64 + j*16 + lm;
                float bz = dpb[col];
                #pragma unroll
                for(int r = 0; r < 4; ++r){
                    float v = acc[i][j][r] + bz;
                    v = (v > 20.f) ? v : __logf(1.f + __expf(v));
                    dv[(row + r)*512L + col] = f2bf(v);
                }
            }
        }
    } else {
        #pragma unroll
        for(int i = 0; i < 4; ++i){
            long row = m0 + wr*64 + i*16 + lq*4;
            #pragma unroll
            for(int j = 0; j < 4; ++j){
                int lcol = wc*64 + j*16 + lm;     // valid < 32
                if(lcol < 32){
                    #pragma unroll
                    for(int r = 0; r < 4; ++r)
                        xdbl32[(row + r)*32L + lcol] = acc[i][j][r];
                }
            }
        }
    }
}

// ---------------- out_proj + residual + LayerNorm fused (tile M=32, 3-stage) ----------------
__global__ __launch_bounds__(256) void gemm_out_ln_kernel(
        const u16* __restrict__ A, const u16* __restrict__ B,
        float* __restrict__ s, u16* __restrict__ xln,
        const float* __restrict__ lw, const float* __restrict__ lb){
    __shared__ u16 Asm[3][32*32];    // 6 KB
    __shared__ u16 Bsm[3][256*32];   // 48 KB
    __shared__ float lnred[2][2][16][2];
    int m0 = blockIdx.x * 32;
    int tid = threadIdx.x;
    int wave = tid >> 6, lane = tid & 63;
    int wr = wave >> 1, wc = wave & 1;
    int lm = lane & 15, lq = lane >> 4;
    int swq = (lq ^ ((lm >> 1) & 3)) * 8;
    const u16* agA[2]; int lda[2];
    #pragma unroll
    for(int it = 0; it < 2; ++it){
        int c = it*256 + tid;
        int r = c >> 4;
        int kp = (c & 15) * 2;
        int kel = ((((c & 15) >> 2) ^ ((r >> 1) & 3)) << 3) + (kp & 7);
        agA[it] = A + (long)(m0 + r)*512 + kel;
        lda[it] = c*2;
    }
    const u16* bg[4]; int ldb[4];
    #pragma unroll
    for(int it = 0; it < 4; ++it){
        int c = it*256 + tid;
        int r = c >> 2;
        int kq = ((c & 3) ^ ((r >> 1) & 3)) * 8;
        bg[it] = B + (long)r*512 + kq;
        ldb[it] = c*8;
    }
    f32x4 acc[8] = {};
    #pragma unroll
    for(int pt = 0; pt < 2; ++pt){
        int ko = pt << 5;
        #pragma unroll
        for(int it = 0; it < 2; ++it) GLL4(agA[it] + ko, &Asm[pt][lda[it]]);
        #pragma unroll
        for(int it = 0; it < 4; ++it) GLL16(bg[it] + ko, &Bsm[pt][ldb[it]]);
    }
    for(int kt = 0; kt < 16; ++kt){
        int cur = kt % 3;
        if(kt + 2 < 16){
            int nxt = (kt + 2) % 3;
            int ko = (kt + 2) << 5;
            #pragma unroll
            for(int it = 0; it < 2; ++it) GLL4(agA[it] + ko, &Asm[nxt][lda[it]]);
            #pragma unroll
            for(int it = 0; it < 4; ++it) GLL16(bg[it] + ko, &Bsm[nxt][ldb[it]]);
            VMW(12);
        } else if(kt + 1 < 16){
            VMW(6);
        } else {
            VMW(0);
        }
        blockbar();
        short8 af = *(const short8*)&Asm[cur][(wr*16 + lm)*32 + swq];
        #pragma unroll
        for(int j = 0; j < 8; ++j){
            short8 bf = *(const short8*)&Bsm[cur][(wc*128 + j*16 + lm)*32 + swq];
            acc[j] = __builtin_amdgcn_mfma_f32_16x16x32_bf16(af, bf, acc[j], 0, 0, 0);
        }
        __builtin_amdgcn_sched_barrier(0);
        blockbar();
    }
    int row0 = m0 + wr*16 + lq*4;
    float psum[4] = {0.f,0.f,0.f,0.f}, psq[4] = {0.f,0.f,0.f,0.f};
    #pragma unroll
    for(int j = 0; j < 8; ++j){
        int col = wc*128 + j*16 + lm;
        #pragma unroll
        for(int r = 0; r < 4; ++r){
            long idx = (long)(row0 + r)*HID + col;
            float v = s[idx] + acc[j][r];
            acc[j][r] = v;
            s[idx] = v;
            psum[r] += v; psq[r] += v*v;
        }
    }
    #pragma unroll
    for(int mask = 1; mask <= 8; mask <<= 1){
        #pragma unroll
        for(int r = 0; r < 4; ++r){
            psum[r] += __shfl_xor(psum[r], mask);
            psq[r]  += __shfl_xor(psq[r],  mask);
        }
    }
    if(lm == 0){
        #pragma unroll
        for(int r = 0; r < 4; ++r){
            lnred[wr][wc][lq*4 + r][0] = psum[r];
            lnred[wr][wc][lq*4 + r][1] = psq[r];
        }
    }
    __syncthreads();
    float mean[4], rstd[4];
    #pragma unroll
    for(int r = 0; r < 4; ++r){
        float t  = lnred[wr][0][lq*4 + r][0] + lnred[wr][1][lq*4 + r][0];
        float tt = lnred[wr][0][lq*4 + r][1] + lnred[wr][1][lq*4 + r][1];
        mean[r] = t * (1.f/256.f);
        float var = tt * (1.f/256.f) - mean[r]*mean[r];
        rstd[r] = rsqrtf(var + 1e-5f);
    }
    #pragma unroll
    for(int j = 0; j < 8; ++j){
        int col = wc*128 + j*16 + lm;
        float wv = lw[col], bv = lb[col];
        #pragma unroll
        for(int r = 0; r < 4; ++r){
            long idx = (long)(row0 + r)*HID + col;
            xln[idx] = f2bf((acc[j][r] - mean[r]) * rstd[r] * wv + bv);
        }
    }
}

// ---------------- scan phase 1: per-chunk (prod a, h_end); chunk-major outputs ----------------
__global__ __launch_bounds__(256) void scan1_kernel(
        const u16* __restrict__ xcvb, const u16* __restrict__ dvin,
        const float* __restrict__ xdbl32, const float* __restrict__ Alog,
        float* __restrict__ aprod, float* __restrict__ hend){
    int d = blockIdx.y * 256 + threadIdx.x;
    int c = blockIdx.x;
    int b = blockIdx.z;
    __shared__ float bm[LCH][16];
    {
        int t = threadIdx.x >> 4, n = threadIdx.x & 15;
        #pragma unroll
        for(int it = 0; it < 4; ++it){
            long p = ((long)(b*LSEQ + c*LCH + t + it*16))*32;
            bm[t + it*16][n] = xdbl32[p + n];
        }
    }
    __syncthreads();
    float An[16];
    #pragma unroll
    for(int n = 0; n < 16; ++n)
        An[n] = -__expf(Alog[d*16 + n]);
    float An0 = An[0];
    bool structural = true;
    #pragma unroll
    for(int n = 0; n < 16; ++n)
        structural = structural && (fabsf(An[n] - (float)(n+1)*An0) <= 1e-3f*(float)(n+1));
    long base = ((long)(b*LSEQ + c*LCH))*DIN + d;
    long ob = (long)c*32768 + ((long)b*DIN + d)*16;   // chunk-major
    if(structural){
        f32x2 h2[8];
        #pragma unroll
        for(int i = 0; i < 8; ++i) h2[i] = (f32x2){0.f, 0.f};
        float sumdv = 0.f;
        float xv_n = bf2f(xcvb[base]);
        float dv_n = bf2f(dvin[base]);
        for(int t = 0; t < LCH; ++t){
            float xv = xv_n, dv = dv_n;
            if(t + 1 < LCH){
                xv_n = bf2f(xcvb[base + (long)(t+1)*DIN]);
                dv_n = bf2f(dvin[base + (long)(t+1)*DIN]);
            }
            sumdv += dv;
            float db = dv * xv;
            float r1 = __expf(dv * An0);
            float r2 = r1 * r1;
            f32x2 rr = {r2, r2};
            f32x2 e2[8];
            e2[0] = (f32x2){r1, r2};
            #pragma unroll
            for(int i = 1; i < 8; ++i) e2[i] = e2[i-1] * rr;
            f32x2 db2 = {db, db};
            const f32x2* b2 = (const f32x2*)&bm[t][0];
            #pragma unroll
            for(int i = 0; i < 8; ++i) h2[i] = e2[i]*h2[i] + db2*b2[i];
        }
        float R = __expf(An0 * sumdv);
        float Rp = R;
        const float* hp = (const float*)h2;
        #pragma unroll
        for(int n = 0; n < 16; ++n){
            aprod[ob+n] = Rp; Rp *= R;
            hend[ob+n] = hp[n];
        }
    } else {
        float h[16], ap[16];
        #pragma unroll
        for(int n = 0; n < 16; ++n){ h[n] = 0.f; ap[n] = 1.f; }
        for(int t = 0; t < LCH; ++t){
            float dv = bf2f(dvin[base + (long)t*DIN]);
            float db = dv * bf2f(xcvb[base + (long)t*DIN]);
            #pragma unroll
            for(int n = 0; n < 16; ++n){
                float e = __expf(dv * An[n]);
                ap[n] *= e;
                h[n] = fmaf(e, h[n], db * bm[t][n]);
            }
        }
        #pragma unroll
        for(int n = 0; n < 16; ++n){ aprod[ob+n] = ap[n]; hend[ob+n] = h[n]; }
    }
}

// ---------------- scan phase 2: sequential combine; fully coalesced (chunk-major) ----------------
__global__ void scan2_kernel(const float* __restrict__ aprod, const float* __restrict__ hend,
                             float* __restrict__ hinit){
    int gtid = blockIdx.x * 256 + threadIdx.x;    // 32768
    const long S = 32768;
    float h = 0.f;
    for(int cc = 0; cc < NCHUNK; cc += 8){
        float a[8], e[8];
        #pragma unroll
        for(int j = 0; j < 8; ++j){
            long p = (long)(cc + j)*S + gtid;
            a[j] = aprod[p]; e[j] = hend[p];
        }
        #pragma unroll
        for(int j = 0; j < 8; ++j){
            hinit[(long)(cc + j)*S + gtid] = h;
            h = fmaf(a[j], h, e[j]);
        }
    }
}

// ---------------- scan phase 3: replay + epilogue -> bf16 y ----------------
__global__ __launch_bounds__(256) void scan3_kernel(
        const u16* __restrict__ xcvb, const u16* __restrict__ dvin,
        const float* __restrict__ xdbl32, const float* __restrict__ Alog,
        const float* __restrict__ hinit, const float* __restrict__ Dp,
        const u16* __restrict__ xz, u16* __restrict__ yout){
    int d = blockIdx.y * 256 + threadIdx.x;
    int c = blockIdx.x;
    int b = blockIdx.z;
    __shared__ float bm[LCH][16], cm[LCH][16];
    {
        int t = threadIdx.x >> 4, n = threadIdx.x & 15;
        #pragma unroll
        for(int it = 0; it < 4; ++it){
            long p = ((long)(b*LSEQ + c*LCH + t + it*16))*32;
            bm[t + it*16][n] = xdbl32[p + n];
            cm[t + it*16][n] = xdbl32[p + 16 + n];
        }
    }
    __syncthreads();
    float An[16];
    long hb = (long)c*32768 + ((long)b*DIN + d)*16;   // chunk-major
    #pragma unroll
    for(int n = 0; n < 16; ++n)
        An[n] = -__expf(Alog[d*16 + n]);
    float An0 = An[0];
    bool structural = true;
    #pragma unroll
    for(int n = 0; n < 16; ++n)
        structural = structural && (fabsf(An[n] - (float)(n+1)*An0) <= 1e-3f*(float)(n+1));
    float Dv = Dp[d];
    long base  = ((long)(b*LSEQ + c*LCH))*DIN + d;
    long zbase = ((long)(b*LSEQ + c*LCH))*(2*DIN) + DIN + d;
    if(structural){
        f32x2 h2[8];
        {
            const f32x2* hi = (const f32x2*)&hinit[hb];
            #pragma unroll
            for(int i = 0; i < 8; ++i) h2[i] = hi[i];
        }
        float xv_n = bf2f(xcvb[base]);
        float z_n  = bf2f(xz[zbase]);
        float dv_n = bf2f(dvin[base]);
        for(int t = 0; t < LCH; ++t){
            float xv = xv_n, z = z_n, dv = dv_n;
            if(t + 1 < LCH){
                xv_n = bf2f(xcvb[base + (long)(t+1)*DIN]);
                z_n  = bf2f(xz[zbase + (long)(t+1)*(2*DIN)]);
                dv_n = bf2f(dvin[base + (long)(t+1)*DIN]);
            }
            float db = dv * xv;
            float r1 = __expf(dv * An0);
            float r2 = r1 * r1;
            f32x2 rr = {r2, r2};
            f32x2 e2[8];
            e2[0] = (f32x2){r1, r2};
            #pragma unroll
            for(int i = 1; i < 8; ++i) e2[i] = e2[i-1] * rr;
            f32x2 db2 = {db, db};
            const f32x2* b2 = (const f32x2*)&bm[t][0];
            const f32x2* c2 = (const f32x2*)&cm[t][0];
            f32x2 y2 = {0.f, 0.f};
            #pragma unroll
            for(int i = 0; i < 8; ++i){
                h2[i] = e2[i]*h2[i] + db2*b2[i];
                y2 = y2 + h2[i]*c2[i];
            }
            float y = y2[0] + y2[1];
            y = fmaf(xv, Dv, y);
            yout[base + (long)t*DIN] = f2bf(y * dsilu(z));
        }
    } else {
        float h[16];
        #pragma unroll
        for(int n = 0; n < 16; ++n) h[n] = hinit[hb + n];
        for(int t = 0; t < LCH; ++t){
            float dv = bf2f(dvin[base + (long)t*DIN]);
            float xv = bf2f(xcvb[base + (long)t*DIN]);
            float db = dv * xv;
            float y = 0.f;
            #pragma unroll
            for(int n = 0; n < 16; ++n){
                float e = __expf(dv * An[n]);
                h[n] = fmaf(e, h[n], db * bm[t][n]);
                y = fmaf(h[n], cm[t][n], y);
            }
            y = fmaf(xv, Dv, y);
            float z = bf2f(xz[zbase + (long)t*(2*DIN)]);
            yout[base + (long)t*DIN] = f2bf(y * dsilu(z));
        }
    }
}

// ---------------- final copy ----------------
__global__ void copyout_kernel(const float* __restrict__ s, float* __restrict__ out, int out_size){
    int idx = blockIdx.x * 256 + threadIdx.x;
    if(idx >= out_size) return;
    out[idx] = (idx < BB*LSEQ*HID) ? s[idx] : 64.0f;
}

extern "C" void kernel_launch(void* const* d_in, const int* in_sizes, int n_in,
                              void* d_out, int out_size, void* d_ws, size_t ws_size,
                              hipStream_t stream){
    const float* x        = (const float*)d_in[0];
    const float* conv1_w  = (const float*)d_in[1];
    const float* conv1_b  = (const float*)d_in[2];
    const float* gn1_w    = (const float*)d_in[3];
    const float* gn1_b    = (const float*)d_in[4];
    const float* conv2_w  = (const float*)d_in[5];
    const float* conv2_b  = (const float*)d_in[6];
    const float* gn2_w    = (const float*)d_in[7];
    const float* gn2_b    = (const float*)d_in[8];
    const float* ln_w     = (const float*)d_in[9];
    const float* ln_b     = (const float*)d_in[10];
    const float* in_proj  = (const float*)d_in[11];
    const float* c1d_w    = (const float*)d_in[12];
    const float* c1d_b    = (const float*)d_in[13];
    const float* x_proj   = (const float*)d_in[14];
    const float* dt_w     = (const float*)d_in[15];
    const float* dt_b     = (const float*)d_in[16];
    const float* A_log    = (const float*)d_in[17];
    const float* Dvec     = (const float*)d_in[18];
    const float* out_proj = (const float*)d_in[19];

    float* ws = (float*)d_ws;
    float* s      = ws;                       // 4,194,304 f
    u16*   xz_bf  = (u16*)(ws + 4194304);     // 16,777,216 u16 (z half used)
    float* y1     = ws + 4194304;             // alias: y1 fp32 (stem only)
    u16*   xt     = (u16*)(ws + 12582912);    // 8,652,800 u16
    u16*   xcv_bf = (u16*)(ws + 16909312);    // 8,388,608 u16
    float* y2t    = ws + 16909312;            // alias: y2t fp32 (stem only)
    u16*   xln_bf = (u16*)(ws + 21103616);    // 4,194,304 u16
    float* xdbl   = ws + 23200768;            // 524,288 f (16384 x 32)
    float* aprod  = ws + 23987200;            // 2,097,152 f used (slot 4,194,304 f)
    float* hendb  = ws + 28181504;            // 2,097,152 f used
    u16*   y_bf   = (u16*)aprod;              // alias: y (8,388,608 u16) fits in aprod slot
    float* hinit  = ws + 32375808;            // 2,097,152 f used
    float* stats  = ws + 36570112;            // 128 f (GN1: 0..63, GN2: 64..127)
    u16*   ipw_bf = (u16*)(ws + 36570240);    // 1,048,576 u16
    u16*   opw_bf = ipw_bf + 1048576;         //   524,288 u16
    u16*   c2w_bf = opw_bf + 524288;          //   294,912 u16
    u16*   dv_bf  = (u16*)(ws + 37635264);    // 8,388,608 u16
    u16*   wcomb  = (u16*)(ws + 41829568);    // 1,310,720 u16

    // ---- prep (1 launch): weight casts + wcomb + xt border + stats zero ----
    prep_kernel<<<12933, 256, 0, stream>>>(in_proj, out_proj, conv2_w, x_proj, dt_w,
                                           ipw_bf, opw_bf, c2w_bf, wcomb,
                                           (unsigned*)xt, stats);

    // ---- stem ----
    conv1_kernel<<<dim3(128,4), 256, 0, stream>>>(x, conv1_w, conv1_b, y1, stats);
    gn1_transform_kernel<<<dim3(4,4,512), dim3(32,8), 0, stream>>>(y1, stats, gn1_w, gn1_b, xt);
    conv2gemm_bf16_kernel<<<dim3(256,2), 256, 0, stream>>>(xt, c2w_bf, conv2_b, y2t, stats);
    gn2t_apply_ln_kernel<<<16384, 256, 0, stream>>>(y2t, stats, gn2_w, gn2_b,
                                                    ln_w, ln_b, s, xln_bf);

    // ---- 4 mamba layers ----
    for(int layer = 0; layer < NL; ++layer){
        const float* cw  = c1d_w + (long)layer*DIN*4;
        const float* cb  = c1d_b + (long)layer*DIN;
        const float* dpb = dt_b  + (long)layer*DIN;
        const float* Al  = A_log + (long)layer*DIN*DST;
        const float* Dl  = Dvec  + (long)layer*DIN;
        int lnext = (layer + 1) & 3;

        gemm_inproj_conv_kernel<<<dim3(128,8), 256, 0, stream>>>(
            xln_bf, ipw_bf + (long)layer*1024*256, xz_bf, xcv_bf, cw, cb);
        gemm_dtbc_kernel<<<dim3(128,5), 256, 0, stream>>>(
            xcv_bf, wcomb + (long)layer*640*512, dpb, dv_bf, xdbl);
        scan1_kernel<<<dim3(NCHUNK,2,BB), 256, 0, stream>>>(
            xcv_bf, dv_bf, xdbl, Al, aprod, hendb);
        scan2_kernel<<<128, 256, 0, stream>>>(aprod, hendb, hinit);
        scan3_kernel<<<dim3(NCHUNK,2,BB), 256, 0, stream>>>(
            xcv_bf, dv_bf, xdbl, Al, hinit, Dl, xz_bf, y_bf);
        gemm_out_ln_kernel<<<512, 256, 0, stream>>>(
            y_bf, opw_bf + (long)layer*256*512, s, xln_bf,
            ln_w + lnext*HID, ln_b + lnext*HID);
    }

    copyout_kernel<<<(out_size + 255)/256, 256, 0, stream>>>(s, (float*)d_out, out_size);
}

// Round 6
// 766.748 us; speedup vs baseline: 3.0987x; 1.8107x over previous
//
#include <hip/hip_runtime.h>
#include <math.h>

#define BB 4
#define C1 128
#define H1 128
#define W1 128
#define C2 256
#define H2 64
#define W2 64
#define LSEQ 4096
#define HID 256
#define DIN 512
#define DST 16
#define DTR 16
#define NL 4
#define NCHUNK 64
#define LCH 64

typedef unsigned short u16;
using short8 = __attribute__((ext_vector_type(8))) short;
using f32x4  = __attribute__((ext_vector_type(4))) float;
using f32x2  = __attribute__((ext_vector_type(2))) float;

static __device__ __forceinline__ float dsilu(float x){
    return x / (1.0f + __expf(-x));
}
static __device__ __forceinline__ u16 f2bf(float f){
    unsigned u = __float_as_uint(f);
    u += 0x7FFF + ((u >> 16) & 1);
    return (u16)(u >> 16);
}
static __device__ __forceinline__ float bf2f(u16 v){
    return __uint_as_float(((unsigned)v) << 16);
}

#define GLL16(g, l) __builtin_amdgcn_global_load_lds( \
    (const __attribute__((address_space(1))) void*)(g), \
    (__attribute__((address_space(3))) void*)(l), 16, 0, 0)
#define GLL4(g, l) __builtin_amdgcn_global_load_lds( \
    (const __attribute__((address_space(1))) void*)(g), \
    (__attribute__((address_space(3))) void*)(l), 4, 0, 0)

#define VMW(n) asm volatile("s_waitcnt vmcnt(" #n ")" ::: "memory")

static __device__ __forceinline__ void blockbar(){
    asm volatile("" ::: "memory");
    __builtin_amdgcn_s_barrier();
    asm volatile("" ::: "memory");
}

// ---------------- mega prep: bf16 weight casts + wcomb + xt border + stats zero ----------------
__global__ void prep_kernel(const float* __restrict__ in_proj, const float* __restrict__ out_proj,
                            const float* __restrict__ conv2_w, const float* __restrict__ xpw,
                            const float* __restrict__ dpw,
                            u16* __restrict__ ipw_bf, u16* __restrict__ opw_bf,
                            u16* __restrict__ c2w_bf, u16* __restrict__ wcomb,
                            unsigned* __restrict__ xt, float* __restrict__ stats){
    int bx = blockIdx.x, tid = threadIdx.x;
    if(bx < 4096){
        int idx = bx*256 + tid;
        ipw_bf[idx] = f2bf(in_proj[idx]);
        return;
    }
    bx -= 4096;
    if(bx < 2048){
        int idx = bx*256 + tid;
        opw_bf[idx] = f2bf(out_proj[idx]);
        return;
    }
    bx -= 2048;
    if(bx < 1152){
        int idx = bx*256 + tid;      // 294912
        int ci = idx & 127, p = (idx >> 7) % 9, co = idx / (9*128);
        int kh = p / 3, kw = p - 3*kh;
        c2w_bf[idx] = f2bf(conv2_w[((co*128 + ci)*3 + kh)*3 + kw]);
        return;
    }
    bx -= 1152;
    if(bx < 5120){
        int idx = bx*256 + tid;      // 1,310,720
        int k = idx & 511;
        int n = (idx >> 9) % 640;
        int layer = idx / (640*512);
        u16 val = 0;
        if(n < 512){
            const float* dp = dpw + ((long)layer*512 + n)*16;
            const float* xp = xpw + (long)layer*48*512 + k;
            float acc = 0.f;
            #pragma unroll
            for(int r = 0; r < 16; ++r) acc = fmaf(dp[r], xp[(long)r*512], acc);
            val = f2bf(acc);
        } else if(n < 544){
            int row = n - 512 + 16;
            val = f2bf(xpw[((long)layer*48 + row)*512 + k]);
        }
        wcomb[((long)layer*640 + n)*512 + k] = val;
        return;
    }
    bx -= 5120;
    if(bx < 516){
        int idx = bx*256 + tid;      // 132,096
        int c2 = idx & 63;
        int cell = (idx >> 6) % 516;
        int b = idx / (516*64);
        int ih, iw;
        if(cell < 130){ ih = 0; iw = cell; }
        else if(cell < 260){ ih = 129; iw = cell - 130; }
        else if(cell < 388){ iw = 0; ih = cell - 259; }
        else { iw = 129; ih = cell - 387; }
        xt[((long)(b*130 + ih)*130 + iw)*64 + c2] = 0;
        return;
    }
    // last block: zero stats (GN1: 0..63, GN2: 64..127)
    if(tid < 128) stats[tid] = 0.f;
}

// ---------------- conv1 via LDS row staging + fused GN1 stats ----------------
__global__ __launch_bounds__(256) void conv1_kernel(
        const float* __restrict__ x, const float* __restrict__ w,
        const float* __restrict__ bias, float* __restrict__ y,
        float* __restrict__ stats){
    __shared__ float xs[9][260];
    int oh = blockIdx.x, b = blockIdx.y;
    int tid = threadIdx.x;
    #pragma unroll
    for(int r = 0; r < 9; ++r){
        int ci = r / 3, kh = r - 3*ci;
        int ih = 2*oh - 1 + kh;
        float v = 0.f;
        if(ih >= 0) v = x[((b*3 + ci)*256 + ih)*256 + tid];
        xs[r][tid + 1] = v;
        if(tid == 0) xs[r][0] = 0.f;
    }
    __syncthreads();
    int co = tid >> 1, h = tid & 1;
    float wr[27];
    #pragma unroll
    for(int j = 0; j < 27; ++j) wr[j] = w[co*27 + j];
    float bz = bias[co];
    long obase = ((long)((b*128 + co)*128 + oh))*128 + h*64;
    float s = 0.f, ss = 0.f;
    #pragma unroll 4
    for(int i = 0; i < 64; ++i){
        int iw0 = 2*(h*64 + i);
        float acc = bz;
        #pragma unroll
        for(int r = 0; r < 9; ++r){
            acc = fmaf(xs[r][iw0+0], wr[r*3+0], acc);
            acc = fmaf(xs[r][iw0+1], wr[r*3+1], acc);
            acc = fmaf(xs[r][iw0+2], wr[r*3+2], acc);
        }
        y[obase + i] = acc;
        s += acc; ss += acc*acc;
    }
    // GN1 group = co>>4 = tid>>5: 32 consecutive threads per group
    #pragma unroll
    for(int off = 16; off; off >>= 1){
        s  += __shfl_down(s,  off);
        ss += __shfl_down(ss, off);
    }
    if((tid & 31) == 0){
        int g = b*8 + (tid >> 5);
        atomicAdd(&stats[g], s);
        atomicAdd(&stats[32 + g], ss);
    }
}

// ---------------- GN1 apply + SiLU + NCHW -> padded channels-last bf16 ----------------
__global__ void gn1_transform_kernel(const float* __restrict__ y1, const float* __restrict__ stats,
                                     const float* __restrict__ w, const float* __restrict__ bias,
                                     u16* __restrict__ xt){
    __shared__ float tile[32][33];
    int b = blockIdx.z >> 7, ih = blockIdx.z & 127;
    int c0 = blockIdx.y * 32, w0 = blockIdx.x * 32;
    int tx = threadIdx.x, ty = threadIdx.y;   // 32 x 8
    const float cnt = 16.f * 128.f * 128.f;
    #pragma unroll
    for(int i = 0; i < 4; ++i){
        int ci = c0 + ty + i*8;
        int g = b*8 + (ci >> 4);
        float mean = stats[g] / cnt;
        float var  = stats[32+g] / cnt - mean*mean;
        float rstd = rsqrtf(var + 1e-5f);
        float v = y1[(((long)(b*C1 + ci))*H1 + ih)*W1 + w0 + tx];
        tile[ty + i*8][tx] = dsilu((v - mean) * rstd * w[ci] + bias[ci]);
    }
    __syncthreads();
    #pragma unroll
    for(int i = 0; i < 4; ++i){
        int iwl = ty + i*8;
        xt[((long)(b*130 + ih + 1)*130 + (w0 + iwl + 1))*128 + c0 + tx] = f2bf(tile[tx][iwl]);
    }
}

// ---------------- conv2 implicit GEMM (tile 64x128, 3-stage) ----------------
__global__ __launch_bounds__(256) void conv2gemm_bf16_kernel(
        const u16* __restrict__ xt, const u16* __restrict__ w2,
        const float* __restrict__ bias, float* __restrict__ y2t){
    __shared__ u16 Asm[3][64*32];    // 12 KB
    __shared__ u16 Bsm[3][128*32];   // 24 KB
    int m0 = blockIdx.x * 64, n0 = blockIdx.y * 128;
    int tid = threadIdx.x;
    long abase;
    {
        int r = tid >> 2;
        int kq = ((tid & 3) ^ ((r >> 1) & 3)) * 8;
        int m = m0 + r;
        int b = m >> 12, oh = (m >> 6) & 63, ow = m & 63;
        abase = ((long)(b*130 + 2*oh)*130 + 2*ow)*128 + kq;
    }
    int lda = tid*8;
    const u16* bbase[2]; int ldb[2];
    #pragma unroll
    for(int it = 0; it < 2; ++it){
        int c = it*256 + tid;
        int r = c >> 2;
        int kq = ((c & 3) ^ ((r >> 1) & 3)) * 8;
        bbase[it] = w2 + (long)(n0 + r)*1152 + kq;
        ldb[it] = c*8;
    }
    int wave = tid >> 6, lane = tid & 63;
    int wr = wave >> 1, wc = wave & 1;
    int lm = lane & 15, lq = lane >> 4;
    int swq = (lq ^ ((lm >> 1) & 3)) * 8;
    f32x4 acc[2][4] = {};
    #pragma unroll
    for(int pt = 0; pt < 2; ++pt){
        int p = pt >> 2, cs = pt & 3;
        int kh = p / 3, kw = p - 3*kh;
        int ao = (kh*130 + kw)*128 + cs*32;
        GLL16(xt + abase + ao, &Asm[pt][lda]);
        #pragma unroll
        for(int it = 0; it < 2; ++it)
            GLL16(bbase[it] + pt*32, &Bsm[pt][ldb[it]]);
    }
    for(int kk = 0; kk < 36; ++kk){
        int cur = kk % 3;
        if(kk + 2 < 36){
            int k2 = kk + 2;
            int nxt = (kk + 2) % 3;
            int p = k2 >> 2, cs = k2 & 3;
            int kh = p / 3, kw = p - 3*kh;
            int ao = (kh*130 + kw)*128 + cs*32;
            GLL16(xt + abase + ao, &Asm[nxt][lda]);
            #pragma unroll
            for(int it = 0; it < 2; ++it)
                GLL16(bbase[it] + k2*32, &Bsm[nxt][ldb[it]]);
            VMW(6);
        } else if(kk + 1 < 36){
            VMW(3);
        } else {
            VMW(0);
        }
        blockbar();
        short8 af[2], bf[4];
        #pragma unroll
        for(int i = 0; i < 2; ++i)
            af[i] = *(const short8*)&Asm[cur][(wr*32 + i*16 + lm)*32 + swq];
        #pragma unroll
        for(int j = 0; j < 4; ++j)
            bf[j] = *(const short8*)&Bsm[cur][(wc*64 + j*16 + lm)*32 + swq];
        #pragma unroll
        for(int i = 0; i < 2; ++i)
            #pragma unroll
            for(int j = 0; j < 4; ++j)
                acc[i][j] = __builtin_amdgcn_mfma_f32_16x16x32_bf16(af[i], bf[j], acc[i][j], 0, 0, 0);
        __builtin_amdgcn_sched_barrier(0);
        blockbar();
    }
    #pragma unroll
    for(int i = 0; i < 2; ++i){
        long row = m0 + wr*32 + i*16 + lq*4;
        #pragma unroll
        for(int j = 0; j < 4; ++j){
            int col = n0 + wc*64 + j*16 + lm;
            float bz = bias[col];
            #pragma unroll
            for(int r = 0; r < 4; ++r)
                y2t[(row + r)*256L + col] = acc[i][j][r] + bz;
        }
    }
}

// ---------------- GN2 stats over [m][c] (standalone, writes stats[64..127]) ----------------
__global__ void gn2t_stats_kernel(const float* __restrict__ y2t, float* __restrict__ stats){
    int b = blockIdx.y;
    long row0 = (long)b*LSEQ + blockIdx.x*64;
    int c = threadIdx.x;
    float s = 0.f, ss = 0.f;
    for(int r = 0; r < 64; ++r){
        float v = y2t[(row0 + r)*C2 + c];
        s += v; ss += v*v;
    }
    #pragma unroll
    for(int off = 16; off; off >>= 1){
        s  += __shfl_down(s,  off);
        ss += __shfl_down(ss, off);
    }
    if((c & 31) == 0){
        int g = b*8 + (c >> 5);
        atomicAdd(&stats[64 + g], s);
        atomicAdd(&stats[96 + g], ss);
    }
}

// ---------------- GN2 apply + SiLU -> s, fused LayerNorm(layer 0) -> xln_bf ----------------
__global__ void gn2t_apply_ln_kernel(const float* __restrict__ y2t, const float* __restrict__ stats,
                                     const float* __restrict__ gw, const float* __restrict__ gb,
                                     const float* __restrict__ lw, const float* __restrict__ lb,
                                     float* __restrict__ s, u16* __restrict__ xln){
    long row = blockIdx.x;                        // 16384 rows
    int c = threadIdx.x;                          // 256
    int b = (int)(row >> 12);
    int g = b*8 + (c >> 5);
    const float cnt = 32.f * (float)LSEQ;
    float mean = stats[64+g] / cnt;
    float var  = stats[96+g] / cnt - mean*mean;
    float rstd = rsqrtf(var + 1e-5f);
    float v = dsilu((y2t[row*HID + c] - mean) * rstd * gw[c] + gb[c]);
    s[row*HID + c] = v;
    float sm = v, sq = v*v;
    #pragma unroll
    for(int off = 32; off; off >>= 1){
        sm += __shfl_down(sm, off);
        sq += __shfl_down(sq, off);
    }
    __shared__ float pa[4], pb[4], res[2];
    int wid = c >> 6, lane = c & 63;
    if(lane == 0){ pa[wid] = sm; pb[wid] = sq; }
    __syncthreads();
    if(c == 0){
        float t  = pa[0]+pa[1]+pa[2]+pa[3];
        float tt = pb[0]+pb[1]+pb[2]+pb[3];
        float m2 = t / 256.f;
        float v2 = tt / 256.f - m2*m2;
        res[0] = m2; res[1] = rsqrtf(v2 + 1e-5f);
    }
    __syncthreads();
    xln[row*HID + c] = f2bf((v - res[0]) * res[1] * lw[c] + lb[c]);
}

// ---------------- in_proj GEMM + fused causal conv1d(k=4)+SiLU epilogue ----------------
// A = xln [16384][256], B = ipw [1024][256]. n0<512: conv+silu -> xcv; n0>=512: z -> xz.
__global__ __launch_bounds__(256) void gemm_inproj_conv_kernel(
        const u16* __restrict__ A, const u16* __restrict__ B,
        u16* __restrict__ xz, u16* __restrict__ xcv,
        const float* __restrict__ cw, const float* __restrict__ cb){
    __shared__ u16 smem[24576];   // Asm[3][4096] | Bsm[3][4096]; reused as xcs[131][128]
    u16* Abuf = smem;
    u16* Bbuf = smem + 12288;
    int m0 = blockIdx.x * 128, n0 = blockIdx.y * 128;
    int tid = threadIdx.x;
    int wave = tid >> 6, lane = tid & 63;
    int wr = wave >> 1, wc = wave & 1;
    int lm = lane & 15, lq = lane >> 4;
    int swq = (lq ^ ((lm >> 1) & 3)) * 8;
    const u16* ag[2]; const u16* bg[2]; int ldst[2];
    #pragma unroll
    for(int it = 0; it < 2; ++it){
        int c = it*256 + tid;
        int r = c >> 2;
        int kq = ((c & 3) ^ ((r >> 1) & 3)) * 8;
        ag[it] = A + (long)(m0 + r)*256 + kq;
        bg[it] = B + (long)(n0 + r)*256 + kq;
        ldst[it] = c*8;
    }
    f32x4 acc[4][4] = {};
    #pragma unroll
    for(int pt = 0; pt < 2; ++pt){
        int ko = pt << 5;
        #pragma unroll
        for(int it = 0; it < 2; ++it){
            GLL16(ag[it] + ko, &Abuf[pt*4096 + ldst[it]]);
            GLL16(bg[it] + ko, &Bbuf[pt*4096 + ldst[it]]);
        }
    }
    for(int kt = 0; kt < 8; ++kt){
        int cur = kt % 3;
        if(kt + 2 < 8){
            int nxt = (kt + 2) % 3;
            int ko = (kt + 2) << 5;
            #pragma unroll
            for(int it = 0; it < 2; ++it){
                GLL16(ag[it] + ko, &Abuf[nxt*4096 + ldst[it]]);
                GLL16(bg[it] + ko, &Bbuf[nxt*4096 + ldst[it]]);
            }
            VMW(8);
        } else if(kt + 1 < 8){
            VMW(4);
        } else {
            VMW(0);
        }
        blockbar();
        short8 af[4], bf[4];
        #pragma unroll
        for(int i = 0; i < 4; ++i){
            af[i] = *(const short8*)&Abuf[cur*4096 + (wr*64 + i*16 + lm)*32 + swq];
            bf[i] = *(const short8*)&Bbuf[cur*4096 + (wc*64 + i*16 + lm)*32 + swq];
        }
        #pragma unroll
        for(int i = 0; i < 4; ++i)
            #pragma unroll
            for(int j = 0; j < 4; ++j)
                acc[i][j] = __builtin_amdgcn_mfma_f32_16x16x32_bf16(af[i], bf[j], acc[i][j], 0, 0, 0);
        __builtin_amdgcn_sched_barrier(0);
        blockbar();
    }
    if(n0 >= 512){
        // z half -> xz bf16
        #pragma unroll
        for(int i = 0; i < 4; ++i){
            long row = m0 + wr*64 + i*16 + lq*4;
            #pragma unroll
            for(int j = 0; j < 4; ++j){
                int col = n0 + wc*64 + j*16 + lm;
                #pragma unroll
                for(int r = 0; r < 4; ++r)
                    xz[(row + r)*1024L + col] = f2bf(acc[i][j][r]);
            }
        }
        return;
    }
    // ---- conv epilogue (smem is dead: all LDS reads completed before last barrier) ----
    u16* xcs = smem;   // [131][128]: rows 0..2 = halo (m0-3..m0-1), rows 3..130 = main
    bool first = ((m0 & 4095) == 0);
    for(int jj = tid; jj < 384; jj += 256){
        int hr = jj >> 7, cc = jj & 127;
        u16 val = 0;
        if(!first){
            const u16* ar = A + (long)(m0 - 3 + hr)*256;
            const u16* br = B + (long)(n0 + cc)*256;
            float a2 = 0.f;
            #pragma unroll 4
            for(int k = 0; k < 256; k += 8){
                short8 av = *(const short8*)(ar + k);
                short8 bv = *(const short8*)(br + k);
                #pragma unroll
                for(int q = 0; q < 8; ++q)
                    a2 = fmaf(bf2f((u16)av[q]), bf2f((u16)bv[q]), a2);
            }
            val = f2bf(a2);
        }
        xcs[hr*128 + cc] = val;
    }
    #pragma unroll
    for(int i = 0; i < 4; ++i){
        int rl = wr*64 + i*16 + lq*4;
        #pragma unroll
        for(int j = 0; j < 4; ++j){
            int cl = wc*64 + j*16 + lm;
            #pragma unroll
            for(int r = 0; r < 4; ++r)
                xcs[(3 + rl + r)*128 + cl] = f2bf(acc[i][j][r]);
        }
    }
    __syncthreads();
    {
        int c = tid & 127, h = tid >> 7;
        float4 w4 = *(const float4*)(cw + (n0 + c)*4);
        float bz = cb[n0 + c];
        int r0 = h*64;
        float v0 = bf2f(xcs[(r0+0)*128 + c]);
        float v1 = bf2f(xcs[(r0+1)*128 + c]);
        float v2 = bf2f(xcs[(r0+2)*128 + c]);
        long gbase = (long)(m0 + r0)*512 + n0 + c;
        for(int i2 = 0; i2 < 64; ++i2){
            float v3 = bf2f(xcs[(r0+3+i2)*128 + c]);
            float a2 = fmaf(v0, w4.x, bz);
            a2 = fmaf(v1, w4.y, a2);
            a2 = fmaf(v2, w4.z, a2);
            a2 = fmaf(v3, w4.w, a2);
            xcv[gbase + (long)i2*512] = f2bf(dsilu(a2));
            v0 = v1; v1 = v2; v2 = v3;
        }
    }
}

// ---------------- fused dt-proj (softplus) + x_proj B/C GEMM (3-stage, static MFMA) ----------------
__global__ __launch_bounds__(256) void gemm_dtbc_kernel(
        const u16* __restrict__ A, const u16* __restrict__ B,
        const float* __restrict__ dpb, u16* __restrict__ dv,
        float* __restrict__ xdbl32){
    __shared__ u16 Asm[3][128*32];
    __shared__ u16 Bsm[3][128*32];
    int m0 = blockIdx.x * 128, n0 = blockIdx.y * 128;
    int tid = threadIdx.x;
    int wave = tid >> 6, lane = tid & 63;
    int wr = wave >> 1, wc = wave & 1;
    int lm = lane & 15, lq = lane >> 4;
    int swq = (lq ^ ((lm >> 1) & 3)) * 8;
    const u16* ag[2]; const u16* bg[2]; int ldst[2];
    #pragma unroll
    for(int it = 0; it < 2; ++it){
        int c = it*256 + tid;
        int r = c >> 2;
        int kq = ((c & 3) ^ ((r >> 1) & 3)) * 8;
        ag[it] = A + (long)(m0 + r)*512 + kq;
        bg[it] = B + (long)(n0 + r)*512 + kq;
        ldst[it] = c*8;
    }
    f32x4 acc[4][4] = {};
    #pragma unroll
    for(int pt = 0; pt < 2; ++pt){
        int ko = pt << 5;
        #pragma unroll
        for(int it = 0; it < 2; ++it){
            GLL16(ag[it] + ko, &Asm[pt][ldst[it]]);
            GLL16(bg[it] + ko, &Bsm[pt][ldst[it]]);
        }
    }
    for(int kt = 0; kt < 16; ++kt){
        int cur = kt % 3;
        if(kt + 2 < 16){
            int nxt = (kt + 2) % 3;
            int ko = (kt + 2) << 5;
            #pragma unroll
            for(int it = 0; it < 2; ++it){
                GLL16(ag[it] + ko, &Asm[nxt][ldst[it]]);
                GLL16(bg[it] + ko, &Bsm[nxt][ldst[it]]);
            }
            VMW(8);
        } else if(kt + 1 < 16){
            VMW(4);
        } else {
            VMW(0);
        }
        blockbar();
        short8 af[4], bf[4];
        #pragma unroll
        for(int i = 0; i < 4; ++i){
            af[i] = *(const short8*)&Asm[cur][(wr*64 + i*16 + lm)*32 + swq];
            bf[i] = *(const short8*)&Bsm[cur][(wc*64 + i*16 + lm)*32 + swq];
        }
        #pragma unroll
        for(int i = 0; i < 4; ++i)
            #pragma unroll
            for(int j = 0; j < 4; ++j)
                acc[i][j] = __builtin_amdgcn_mfma_f32_16x16x32_bf16(af[i], bf[j], acc[i][j], 0, 0, 0);
        __builtin_amdgcn_sched_barrier(0);
        blockbar();
    }
    if(n0 < 512){
        #pragma unroll
        for(int i = 0; i < 4; ++i){
            long row = m0 + wr*64 + i*16 + lq*4;
            #pragma unroll
            for(int j = 0; j < 4; ++j){
                int col = n0 + wc*64 + j*16 + lm;
                float bz = dpb[col];
                #pragma unroll
                for(int r = 0; r < 4; ++r){
                    float v = acc[i][j][r] + bz;
                    v = (v > 20.f) ? v : __logf(1.f + __expf(v));
                    dv[(row + r)*512L + col] = f2bf(v);
                }
            }
        }
    } else {
        #pragma unroll
        for(int i = 0; i < 4; ++i){
            long row = m0 + wr*64 + i*16 + lq*4;
            #pragma unroll
            for(int j = 0; j < 4; ++j){
                int lcol = wc*64 + j*16 + lm;     // valid < 32
                if(lcol < 32){
                    #pragma unroll
                    for(int r = 0; r < 4; ++r)
                        xdbl32[(row + r)*32L + lcol] = acc[i][j][r];
                }
            }
        }
    }
}

// ---------------- out_proj + residual + LayerNorm fused (tile M=32, 3-stage) ----------------
__global__ __launch_bounds__(256) void gemm_out_ln_kernel(
        const u16* __restrict__ A, const u16* __restrict__ B,
        float* __restrict__ s, u16* __restrict__ xln,
        const float* __restrict__ lw, const float* __restrict__ lb){
    __shared__ u16 Asm[3][32*32];    // 6 KB
    __shared__ u16 Bsm[3][256*32];   // 48 KB
    __shared__ float lnred[2][2][16][2];
    int m0 = blockIdx.x * 32;
    int tid = threadIdx.x;
    int wave = tid >> 6, lane = tid & 63;
    int wr = wave >> 1, wc = wave & 1;
    int lm = lane & 15, lq = lane >> 4;
    int swq = (lq ^ ((lm >> 1) & 3)) * 8;
    const u16* agA[2]; int lda[2];
    #pragma unroll
    for(int it = 0; it < 2; ++it){
        int c = it*256 + tid;
        int r = c >> 4;
        int kp = (c & 15) * 2;
        int kel = ((((c & 15) >> 2) ^ ((r >> 1) & 3)) << 3) + (kp & 7);
        agA[it] = A + (long)(m0 + r)*512 + kel;
        lda[it] = c*2;
    }
    const u16* bg[4]; int ldb[4];
    #pragma unroll
    for(int it = 0; it < 4; ++it){
        int c = it*256 + tid;
        int r = c >> 2;
        int kq = ((c & 3) ^ ((r >> 1) & 3)) * 8;
        bg[it] = B + (long)r*512 + kq;
        ldb[it] = c*8;
    }
    f32x4 acc[8] = {};
    #pragma unroll
    for(int pt = 0; pt < 2; ++pt){
        int ko = pt << 5;
        #pragma unroll
        for(int it = 0; it < 2; ++it) GLL4(agA[it] + ko, &Asm[pt][lda[it]]);
        #pragma unroll
        for(int it = 0; it < 4; ++it) GLL16(bg[it] + ko, &Bsm[pt][ldb[it]]);
    }
    for(int kt = 0; kt < 16; ++kt){
        int cur = kt % 3;
        if(kt + 2 < 16){
            int nxt = (kt + 2) % 3;
            int ko = (kt + 2) << 5;
            #pragma unroll
            for(int it = 0; it < 2; ++it) GLL4(agA[it] + ko, &Asm[nxt][lda[it]]);
            #pragma unroll
            for(int it = 0; it < 4; ++it) GLL16(bg[it] + ko, &Bsm[nxt][ldb[it]]);
            VMW(12);
        } else if(kt + 1 < 16){
            VMW(6);
        } else {
            VMW(0);
        }
        blockbar();
        short8 af = *(const short8*)&Asm[cur][(wr*16 + lm)*32 + swq];
        #pragma unroll
        for(int j = 0; j < 8; ++j){
            short8 bf = *(const short8*)&Bsm[cur][(wc*128 + j*16 + lm)*32 + swq];
            acc[j] = __builtin_amdgcn_mfma_f32_16x16x32_bf16(af, bf, acc[j], 0, 0, 0);
        }
        __builtin_amdgcn_sched_barrier(0);
        blockbar();
    }
    int row0 = m0 + wr*16 + lq*4;
    float psum[4] = {0.f,0.f,0.f,0.f}, psq[4] = {0.f,0.f,0.f,0.f};
    #pragma unroll
    for(int j = 0; j < 8; ++j){
        int col = wc*128 + j*16 + lm;
        #pragma unroll
        for(int r = 0; r < 4; ++r){
            long idx = (long)(row0 + r)*HID + col;
            float v = s[idx] + acc[j][r];
            acc[j][r] = v;
            s[idx] = v;
            psum[r] += v; psq[r] += v*v;
        }
    }
    #pragma unroll
    for(int mask = 1; mask <= 8; mask <<= 1){
        #pragma unroll
        for(int r = 0; r < 4; ++r){
            psum[r] += __shfl_xor(psum[r], mask);
            psq[r]  += __shfl_xor(psq[r],  mask);
        }
    }
    if(lm == 0){
        #pragma unroll
        for(int r = 0; r < 4; ++r){
            lnred[wr][wc][lq*4 + r][0] = psum[r];
            lnred[wr][wc][lq*4 + r][1] = psq[r];
        }
    }
    __syncthreads();
    float mean[4], rstd[4];
    #pragma unroll
    for(int r = 0; r < 4; ++r){
        float t  = lnred[wr][0][lq*4 + r][0] + lnred[wr][1][lq*4 + r][0];
        float tt = lnred[wr][0][lq*4 + r][1] + lnred[wr][1][lq*4 + r][1];
        mean[r] = t * (1.f/256.f);
        float var = tt * (1.f/256.f) - mean[r]*mean[r];
        rstd[r] = rsqrtf(var + 1e-5f);
    }
    #pragma unroll
    for(int j = 0; j < 8; ++j){
        int col = wc*128 + j*16 + lm;
        float wv = lw[col], bv = lb[col];
        #pragma unroll
        for(int r = 0; r < 4; ++r){
            long idx = (long)(row0 + r)*HID + col;
            xln[idx] = f2bf((acc[j][r] - mean[r]) * rstd[r] * wv + bv);
        }
    }
}

// ---------------- scan phase 1: per-chunk (prod a, h_end); chunk-major outputs ----------------
__global__ __launch_bounds__(256) void scan1_kernel(
        const u16* __restrict__ xcvb, const u16* __restrict__ dvin,
        const float* __restrict__ xdbl32, const float* __restrict__ Alog,
        float* __restrict__ aprod, float* __restrict__ hend){
    int d = blockIdx.y * 256 + threadIdx.x;
    int c = blockIdx.x;
    int b = blockIdx.z;
    __shared__ float bm[LCH][16];
    {
        int t = threadIdx.x >> 4, n = threadIdx.x & 15;
        #pragma unroll
        for(int it = 0; it < 4; ++it){
            long p = ((long)(b*LSEQ + c*LCH + t + it*16))*32;
            bm[t + it*16][n] = xdbl32[p + n];
        }
    }
    __syncthreads();
    float An[16];
    #pragma unroll
    for(int n = 0; n < 16; ++n)
        An[n] = -__expf(Alog[d*16 + n]);
    float An0 = An[0];
    bool structural = true;
    #pragma unroll
    for(int n = 0; n < 16; ++n)
        structural = structural && (fabsf(An[n] - (float)(n+1)*An0) <= 1e-3f*(float)(n+1));
    long base = ((long)(b*LSEQ + c*LCH))*DIN + d;
    long ob = (long)c*32768 + ((long)b*DIN + d)*16;   // chunk-major
    if(structural){
        f32x2 h2[8];
        #pragma unroll
        for(int i = 0; i < 8; ++i) h2[i] = (f32x2){0.f, 0.f};
        float sumdv = 0.f;
        float xv_n = bf2f(xcvb[base]);
        float dv_n = bf2f(dvin[base]);
        for(int t = 0; t < LCH; ++t){
            float xv = xv_n, dv = dv_n;
            if(t + 1 < LCH){
                xv_n = bf2f(xcvb[base + (long)(t+1)*DIN]);
                dv_n = bf2f(dvin[base + (long)(t+1)*DIN]);
            }
            sumdv += dv;
            float db = dv * xv;
            float r1 = __expf(dv * An0);
            float r2 = r1 * r1;
            f32x2 rr = {r2, r2};
            f32x2 e2[8];
            e2[0] = (f32x2){r1, r2};
            #pragma unroll
            for(int i = 1; i < 8; ++i) e2[i] = e2[i-1] * rr;
            f32x2 db2 = {db, db};
            const f32x2* b2 = (const f32x2*)&bm[t][0];
            #pragma unroll
            for(int i = 0; i < 8; ++i) h2[i] = e2[i]*h2[i] + db2*b2[i];
        }
        float R = __expf(An0 * sumdv);
        float Rp = R;
        const float* hp = (const float*)h2;
        #pragma unroll
        for(int n = 0; n < 16; ++n){
            aprod[ob+n] = Rp; Rp *= R;
            hend[ob+n] = hp[n];
        }
    } else {
        float h[16], ap[16];
        #pragma unroll
        for(int n = 0; n < 16; ++n){ h[n] = 0.f; ap[n] = 1.f; }
        for(int t = 0; t < LCH; ++t){
            float dv = bf2f(dvin[base + (long)t*DIN]);
            float db = dv * bf2f(xcvb[base + (long)t*DIN]);
            #pragma unroll
            for(int n = 0; n < 16; ++n){
                float e = __expf(dv * An[n]);
                ap[n] *= e;
                h[n] = fmaf(e, h[n], db * bm[t][n]);
            }
        }
        #pragma unroll
        for(int n = 0; n < 16; ++n){ aprod[ob+n] = ap[n]; hend[ob+n] = h[n]; }
    }
}

// ---------------- scan phase 2: sequential combine; fully coalesced (chunk-major) ----------------
__global__ void scan2_kernel(const float* __restrict__ aprod, const float* __restrict__ hend,
                             float* __restrict__ hinit){
    int gtid = blockIdx.x * 256 + threadIdx.x;    // 32768
    const long S = 32768;
    float h = 0.f;
    for(int cc = 0; cc < NCHUNK; cc += 8){
        float a[8], e[8];
        #pragma unroll
        for(int j = 0; j < 8; ++j){
            long p = (long)(cc + j)*S + gtid;
            a[j] = aprod[p]; e[j] = hend[p];
        }
        #pragma unroll
        for(int j = 0; j < 8; ++j){
            hinit[(long)(cc + j)*S + gtid] = h;
            h = fmaf(a[j], h, e[j]);
        }
    }
}

// ---------------- scan phase 3: replay + epilogue -> bf16 y ----------------
__global__ __launch_bounds__(256) void scan3_kernel(
        const u16* __restrict__ xcvb, const u16* __restrict__ dvin,
        const float* __restrict__ xdbl32, const float* __restrict__ Alog,
        const float* __restrict__ hinit, const float* __restrict__ Dp,
        const u16* __restrict__ xz, u16* __restrict__ yout){
    int d = blockIdx.y * 256 + threadIdx.x;
    int c = blockIdx.x;
    int b = blockIdx.z;
    __shared__ float bm[LCH][16], cm[LCH][16];
    {
        int t = threadIdx.x >> 4, n = threadIdx.x & 15;
        #pragma unroll
        for(int it = 0; it < 4; ++it){
            long p = ((long)(b*LSEQ + c*LCH + t + it*16))*32;
            bm[t + it*16][n] = xdbl32[p + n];
            cm[t + it*16][n] = xdbl32[p + 16 + n];
        }
    }
    __syncthreads();
    float An[16];
    long hb = (long)c*32768 + ((long)b*DIN + d)*16;   // chunk-major
    #pragma unroll
    for(int n = 0; n < 16; ++n)
        An[n] = -__expf(Alog[d*16 + n]);
    float An0 = An[0];
    bool structural = true;
    #pragma unroll
    for(int n = 0; n < 16; ++n)
        structural = structural && (fabsf(An[n] - (float)(n+1)*An0) <= 1e-3f*(float)(n+1));
    float Dv = Dp[d];
    long base  = ((long)(b*LSEQ + c*LCH))*DIN + d;
    long zbase = ((long)(b*LSEQ + c*LCH))*(2*DIN) + DIN + d;
    if(structural){
        f32x2 h2[8];
        {
            const f32x2* hi = (const f32x2*)&hinit[hb];
            #pragma unroll
            for(int i = 0; i < 8; ++i) h2[i] = hi[i];
        }
        float xv_n = bf2f(xcvb[base]);
        float z_n  = bf2f(xz[zbase]);
        float dv_n = bf2f(dvin[base]);
        for(int t = 0; t < LCH; ++t){
            float xv = xv_n, z = z_n, dv = dv_n;
            if(t + 1 < LCH){
                xv_n = bf2f(xcvb[base + (long)(t+1)*DIN]);
                z_n  = bf2f(xz[zbase + (long)(t+1)*(2*DIN)]);
                dv_n = bf2f(dvin[base + (long)(t+1)*DIN]);
            }
            float db = dv * xv;
            float r1 = __expf(dv * An0);
            float r2 = r1 * r1;
            f32x2 rr = {r2, r2};
            f32x2 e2[8];
            e2[0] = (f32x2){r1, r2};
            #pragma unroll
            for(int i = 1; i < 8; ++i) e2[i] = e2[i-1] * rr;
            f32x2 db2 = {db, db};
            const f32x2* b2 = (const f32x2*)&bm[t][0];
            const f32x2* c2 = (const f32x2*)&cm[t][0];
            f32x2 y2 = {0.f, 0.f};
            #pragma unroll
            for(int i = 0; i < 8; ++i){
                h2[i] = e2[i]*h2[i] + db2*b2[i];
                y2 = y2 + h2[i]*c2[i];
            }
            float y = y2[0] + y2[1];
            y = fmaf(xv, Dv, y);
            yout[base + (long)t*DIN] = f2bf(y * dsilu(z));
        }
    } else {
        float h[16];
        #pragma unroll
        for(int n = 0; n < 16; ++n) h[n] = hinit[hb + n];
        for(int t = 0; t < LCH; ++t){
            float dv = bf2f(dvin[base + (long)t*DIN]);
            float xv = bf2f(xcvb[base + (long)t*DIN]);
            float db = dv * xv;
            float y = 0.f;
            #pragma unroll
            for(int n = 0; n < 16; ++n){
                float e = __expf(dv * An[n]);
                h[n] = fmaf(e, h[n], db * bm[t][n]);
                y = fmaf(h[n], cm[t][n], y);
            }
            y = fmaf(xv, Dv, y);
            float z = bf2f(xz[zbase + (long)t*(2*DIN)]);
            yout[base + (long)t*DIN] = f2bf(y * dsilu(z));
        }
    }
}

// ---------------- final copy ----------------
__global__ void copyout_kernel(const float* __restrict__ s, float* __restrict__ out, int out_size){
    int idx = blockIdx.x * 256 + threadIdx.x;
    if(idx >= out_size) return;
    out[idx] = (idx < BB*LSEQ*HID) ? s[idx] : 64.0f;
}

extern "C" void kernel_launch(void* const* d_in, const int* in_sizes, int n_in,
                              void* d_out, int out_size, void* d_ws, size_t ws_size,
                              hipStream_t stream){
    const float* x        = (const float*)d_in[0];
    const float* conv1_w  = (const float*)d_in[1];
    const float* conv1_b  = (const float*)d_in[2];
    const float* gn1_w    = (const float*)d_in[3];
    const float* gn1_b    = (const float*)d_in[4];
    const float* conv2_w  = (const float*)d_in[5];
    const float* conv2_b  = (const float*)d_in[6];
    const float* gn2_w    = (const float*)d_in[7];
    const float* gn2_b    = (const float*)d_in[8];
    const float* ln_w     = (const float*)d_in[9];
    const float* ln_b     = (const float*)d_in[10];
    const float* in_proj  = (const float*)d_in[11];
    const float* c1d_w    = (const float*)d_in[12];
    const float* c1d_b    = (const float*)d_in[13];
    const float* x_proj   = (const float*)d_in[14];
    const float* dt_w     = (const float*)d_in[15];
    const float* dt_b     = (const float*)d_in[16];
    const float* A_log    = (const float*)d_in[17];
    const float* Dvec     = (const float*)d_in[18];
    const float* out_proj = (const float*)d_in[19];

    float* ws = (float*)d_ws;
    float* s      = ws;                       // 4,194,304 f
    u16*   xz_bf  = (u16*)(ws + 4194304);     // 16,777,216 u16 (z half used)
    float* y1     = ws + 4194304;             // alias: y1 fp32 (stem only)
    u16*   xt     = (u16*)(ws + 12582912);    // 8,652,800 u16
    u16*   xcv_bf = (u16*)(ws + 16909312);    // 8,388,608 u16
    float* y2t    = ws + 16909312;            // alias: y2t fp32 (stem only)
    u16*   xln_bf = (u16*)(ws + 21103616);    // 4,194,304 u16
    float* xdbl   = ws + 23200768;            // 524,288 f (16384 x 32)
    float* aprod  = ws + 23987200;            // 2,097,152 f used (slot 4,194,304 f)
    float* hendb  = ws + 28181504;            // 2,097,152 f used
    u16*   y_bf   = (u16*)aprod;              // alias: y (8,388,608 u16) fits in aprod slot
    float* hinit  = ws + 32375808;            // 2,097,152 f used
    float* stats  = ws + 36570112;            // 128 f (GN1: 0..63, GN2: 64..127)
    u16*   ipw_bf = (u16*)(ws + 36570240);    // 1,048,576 u16
    u16*   opw_bf = ipw_bf + 1048576;         //   524,288 u16
    u16*   c2w_bf = opw_bf + 524288;          //   294,912 u16
    u16*   dv_bf  = (u16*)(ws + 37635264);    // 8,388,608 u16
    u16*   wcomb  = (u16*)(ws + 41829568);    // 1,310,720 u16

    // ---- prep (1 launch): weight casts + wcomb + xt border + stats zero ----
    prep_kernel<<<12933, 256, 0, stream>>>(in_proj, out_proj, conv2_w, x_proj, dt_w,
                                           ipw_bf, opw_bf, c2w_bf, wcomb,
                                           (unsigned*)xt, stats);

    // ---- stem ----
    conv1_kernel<<<dim3(128,4), 256, 0, stream>>>(x, conv1_w, conv1_b, y1, stats);
    gn1_transform_kernel<<<dim3(4,4,512), dim3(32,8), 0, stream>>>(y1, stats, gn1_w, gn1_b, xt);
    conv2gemm_bf16_kernel<<<dim3(256,2), 256, 0, stream>>>(xt, c2w_bf, conv2_b, y2t);
    gn2t_stats_kernel<<<dim3(64,4), 256, 0, stream>>>(y2t, stats);
    gn2t_apply_ln_kernel<<<16384, 256, 0, stream>>>(y2t, stats, gn2_w, gn2_b,
                                                    ln_w, ln_b, s, xln_bf);

    // ---- 4 mamba layers ----
    for(int layer = 0; layer < NL; ++layer){
        const float* cw  = c1d_w + (long)layer*DIN*4;
        const float* cb  = c1d_b + (long)layer*DIN;
        const float* dpb = dt_b  + (long)layer*DIN;
        const float* Al  = A_log + (long)layer*DIN*DST;
        const float* Dl  = Dvec  + (long)layer*DIN;
        int lnext = (layer + 1) & 3;

        gemm_inproj_conv_kernel<<<dim3(128,8), 256, 0, stream>>>(
            xln_bf, ipw_bf + (long)layer*1024*256, xz_bf, xcv_bf, cw, cb);
        gemm_dtbc_kernel<<<dim3(128,5), 256, 0, stream>>>(
            xcv_bf, wcomb + (long)layer*640*512, dpb, dv_bf, xdbl);
        scan1_kernel<<<dim3(NCHUNK,2,BB), 256, 0, stream>>>(
            xcv_bf, dv_bf, xdbl, Al, aprod, hendb);
        scan2_kernel<<<128, 256, 0, stream>>>(aprod, hendb, hinit);
        scan3_kernel<<<dim3(NCHUNK,2,BB), 256, 0, stream>>>(
            xcv_bf, dv_bf, xdbl, Al, hinit, Dl, xz_bf, y_bf);
        gemm_out_ln_kernel<<<512, 256, 0, stream>>>(
            y_bf, opw_bf + (long)layer*256*512, s, xln_bf,
            ln_w + lnext*HID, ln_b + lnext*HID);
    }

    copyout_kernel<<<(out_size + 255)/256, 256, 0, stream>>>(s, (float*)d_out, out_size);
}